// Round 4
// baseline (803.933 us; speedup 1.0000x reference)
//
#include <hip/hip_runtime.h>
#include <math.h>

#define ND 20000
#define NF 50000
#define NE 400000
#define NT (NF + ND)     // combined dst nodes (feature first, then device)
// HID=128, H=8, D=16, L=2, IN=128, OUT=32

typedef __attribute__((ext_vector_type(8))) short short8;
typedef __attribute__((ext_vector_type(4))) float f32x4;
typedef unsigned short us;

static __device__ __forceinline__ us f2bf(float f) {
    unsigned u = __builtin_bit_cast(unsigned, f);
    u += 0x7FFF + ((u >> 16) & 1);          // round-to-nearest-even
    return (us)(u >> 16);
}
static __device__ __forceinline__ float bf2f(us h) {
    return __builtin_bit_cast(float, (unsigned)h << 16);
}
static __device__ __forceinline__ float bflo(unsigned u) {
    return __builtin_bit_cast(float, u << 16);
}
static __device__ __forceinline__ float bfhi(unsigned u) {
    return __builtin_bit_cast(float, u & 0xFFFF0000u);
}
static __device__ __forceinline__ float gelu_f(float x) {
    return 0.5f * x * (1.0f + erff(x * 0.70710678118654752f));
}

// ---------------------------------------------------------------------------
// Weight+bias prep. WT[id][c][k] (bf16, pre-transposed), B_all[id][128] fp32.
// id 0: W_dev_in, 1: W_feat_in, 2+lt: Wq, 6+lt: WkF (a_rel & p_rel/4 folded),
// 10+lt: WvF (m_rel folded), 14+lt: Wa.   lt = l*2+t.
// ---------------------------------------------------------------------------
__global__ void prep_all(const float* __restrict__ W_dev_in, const float* __restrict__ W_feat_in,
                         const float* __restrict__ Wq, const float* __restrict__ Wk,
                         const float* __restrict__ Wv, const float* __restrict__ Wa,
                         const float* __restrict__ b_dev_in, const float* __restrict__ b_feat_in,
                         const float* __restrict__ bq, const float* __restrict__ bk,
                         const float* __restrict__ bv, const float* __restrict__ ba,
                         const float* __restrict__ a_rel, const float* __restrict__ m_rel,
                         const float* __restrict__ p_rel,
                         us* __restrict__ WT, float* __restrict__ B_all) {
    int idx = blockIdx.x * 256 + threadIdx.x;
    if (idx < 18 * 16384) {
        int k = idx & 127, c = (idx >> 7) & 127, id = idx >> 14;
        float val;
        if (id == 0) val = W_dev_in[k * 128 + c];
        else if (id == 1) val = W_feat_in[k * 128 + c];
        else if (id < 6) val = Wq[(id - 2) * 16384 + k * 128 + c];
        else if (id < 10) {
            int lt = id - 6, h = c >> 4, e = c & 15;
            const float* A = a_rel + (lt * 8 + h) * 256;
            const float* Ws = Wk + lt * 16384 + k * 128 + h * 16;
            float sm = 0.f;
            #pragma unroll
            for (int d = 0; d < 16; ++d) sm += Ws[d] * A[d * 16 + e];
            val = sm * p_rel[lt * 8 + h] * 0.25f;
        } else if (id < 14) {
            int lt = id - 10, h = c >> 4, e = c & 15;
            const float* A = m_rel + (lt * 8 + h) * 256;
            const float* Ws = Wv + lt * 16384 + k * 128 + h * 16;
            float sm = 0.f;
            #pragma unroll
            for (int d = 0; d < 16; ++d) sm += Ws[d] * A[d * 16 + e];
            val = sm;
        } else val = Wa[(id - 14) * 16384 + k * 128 + c];
        WT[(size_t)id * 16384 + c * 128 + k] = f2bf(val);
    } else {
        int j = idx - 18 * 16384;
        if (j >= 18 * 128) return;
        int c = j & 127, id = j >> 7;
        float v;
        if (id == 0) v = b_dev_in[c];
        else if (id == 1) v = b_feat_in[c];
        else if (id < 6) v = bq[(id - 2) * 128 + c];
        else if (id < 10) {
            int lt = id - 6, h = c >> 4, e = c & 15;
            const float* A = a_rel + (lt * 8 + h) * 256;
            const float* bs = bk + lt * 128 + h * 16;
            float sm = 0.f;
            #pragma unroll
            for (int d = 0; d < 16; ++d) sm += bs[d] * A[d * 16 + e];
            v = sm * p_rel[lt * 8 + h] * 0.25f;
        } else if (id < 14) {
            int lt = id - 10, h = c >> 4, e = c & 15;
            const float* A = m_rel + (lt * 8 + h) * 256;
            const float* bs = bv + lt * 128 + h * 16;
            float sm = 0.f;
            #pragma unroll
            for (int d = 0; d < 16; ++d) sm += bs[d] * A[d * 16 + e];
            v = sm;
        } else v = ba[(id - 14) * 128 + c];
        B_all[j] = v;
    }
}

// ---------------------------------------------------------------------------
// MFMA GEMM over BOTH node types in one dispatch. blockIdx.x < GB0 -> type 0
// (device), else type 1 (feature). blockIdx.y = output plane (q/k/v).
// Weight id = widbase + type + 4*blockIdx.y.
// LNF=1: skip Y store; instead t = x + sk*o + (1-sk)*x, x = LN(t)*g + b
// written in place to the x buffer (row lives in one 16-lane shfl group).
// ---------------------------------------------------------------------------
template<int AF32, int RELU, int LNF>
__global__ __launch_bounds__(256) void mfma_gemm2(
    const void* __restrict__ X0, const void* __restrict__ X1,
    const us* __restrict__ WT0, const float* __restrict__ Ball,
    us* __restrict__ Y0, us* __restrict__ Y1,
    int N0, int N1, int GB0, int widbase,
    us* __restrict__ X0w, us* __restrict__ X1w,
    const float* __restrict__ skipv, const float* __restrict__ lng,
    const float* __restrict__ lnb) {
    const int type = (blockIdx.x >= (unsigned)GB0) ? 1 : 0;
    const int bx = blockIdx.x - (type ? GB0 : 0);
    const int N = type ? N1 : N0;
    const void* Xv = type ? X1 : X0;
    const int wid = widbase + type + 4 * blockIdx.y;
    const us* WT = WT0 + (size_t)wid * 16384;
    const float* bias = Ball + wid * 128;

    const int lane = threadIdx.x & 63;
    const int wave = threadIdx.x >> 6;
    const int row_base = bx * 128 + wave * 32;
    const int l15 = lane & 15, lg = lane >> 4;
    const int kbase = lg * 8;

    short8 a[2][4];
    #pragma unroll
    for (int mf = 0; mf < 2; ++mf) {
        int r = row_base + mf * 16 + l15;
        r = r < N ? r : N - 1;
        if (AF32) {
            const float* Xf = (const float*)Xv + (size_t)r * 128;
            #pragma unroll
            for (int kf = 0; kf < 4; ++kf) {
                float4 lo = *(const float4*)(Xf + kf * 32 + kbase);
                float4 hi = *(const float4*)(Xf + kf * 32 + kbase + 4);
                short8 t;
                t[0] = (short)f2bf(lo.x); t[1] = (short)f2bf(lo.y);
                t[2] = (short)f2bf(lo.z); t[3] = (short)f2bf(lo.w);
                t[4] = (short)f2bf(hi.x); t[5] = (short)f2bf(hi.y);
                t[6] = (short)f2bf(hi.z); t[7] = (short)f2bf(hi.w);
                a[mf][kf] = t;
            }
        } else {
            const us* Xb = (const us*)Xv + (size_t)r * 128;
            #pragma unroll
            for (int kf = 0; kf < 4; ++kf)
                a[mf][kf] = *(const short8*)(Xb + kf * 32 + kbase);
        }
    }

    f32x4 acc[2][8];
    #pragma unroll
    for (int mf = 0; mf < 2; ++mf)
        #pragma unroll
        for (int cf = 0; cf < 8; ++cf) acc[mf][cf] = (f32x4){0.f, 0.f, 0.f, 0.f};

    #pragma unroll
    for (int cf = 0; cf < 8; ++cf) {
        #pragma unroll
        for (int kf = 0; kf < 4; ++kf) {
            short8 b = *(const short8*)(WT + (size_t)(cf * 16 + l15) * 128 + kf * 32 + kbase);
            acc[0][cf] = __builtin_amdgcn_mfma_f32_16x16x32_bf16(a[0][kf], b, acc[0][cf], 0, 0, 0);
            acc[1][cf] = __builtin_amdgcn_mfma_f32_16x16x32_bf16(a[1][kf], b, acc[1][cf], 0, 0, 0);
        }
    }

    float bval[8];
    #pragma unroll
    for (int cf = 0; cf < 8; ++cf) bval[cf] = bias[cf * 16 + l15];

    if (LNF) {
        const int lt = widbase - 14 + type;     // = l*2 + type
        float sk = 1.f / (1.f + __expf(-skipv[lt]));
        float gv[8], bv2[8];
        #pragma unroll
        for (int cf = 0; cf < 8; ++cf) {
            gv[cf]  = lng[(size_t)lt * 128 + cf * 16 + l15];
            bv2[cf] = lnb[(size_t)lt * 128 + cf * 16 + l15];
        }
        us* xw = type ? X1w : X0w;
        #pragma unroll
        for (int mf = 0; mf < 2; ++mf)
            #pragma unroll
            for (int r = 0; r < 4; ++r) {
                int grow = row_base + mf * 16 + lg * 4 + r;   // uniform in shfl-16 group
                if (grow >= N) continue;
                float t[8];
                float sum = 0.f;
                #pragma unroll
                for (int cf = 0; cf < 8; ++cf) {
                    float o = acc[mf][cf][r] + bval[cf];
                    float x = bf2f(xw[(size_t)grow * 128 + cf * 16 + l15]);
                    t[cf] = (2.f - sk) * x + sk * o;
                    sum += t[cf];
                }
                sum += __shfl_xor(sum, 1); sum += __shfl_xor(sum, 2);
                sum += __shfl_xor(sum, 4); sum += __shfl_xor(sum, 8);
                float mean = sum * (1.0f / 128.0f);
                float vs = 0.f;
                #pragma unroll
                for (int cf = 0; cf < 8; ++cf) { t[cf] -= mean; vs += t[cf] * t[cf]; }
                vs += __shfl_xor(vs, 1); vs += __shfl_xor(vs, 2);
                vs += __shfl_xor(vs, 4); vs += __shfl_xor(vs, 8);
                float inv = rsqrtf(vs * (1.0f / 128.0f) + 1e-5f);
                #pragma unroll
                for (int cf = 0; cf < 8; ++cf)
                    xw[(size_t)grow * 128 + cf * 16 + l15] = f2bf(t[cf] * inv * gv[cf] + bv2[cf]);
            }
        return;
    }

    us* Yp = (type ? Y1 : Y0) + (size_t)blockIdx.y * N * 128;
    #pragma unroll
    for (int mf = 0; mf < 2; ++mf)
        #pragma unroll
        for (int r = 0; r < 4; ++r) {
            int grow = row_base + mf * 16 + lg * 4 + r;
            if (grow >= N) continue;
            #pragma unroll
            for (int cf = 0; cf < 8; ++cf) {
                float v = acc[mf][cf][r] + bval[cf];
                if (RELU) v = fmaxf(v, 0.f);
                Yp[(size_t)grow * 128 + cf * 16 + l15] = f2bf(v);
            }
        }
}

// ---------------------------------------------------------------------------
// Final head: Y[N,32](f32) = X(bf16)[N,128] @ W[128,32] + b
// ---------------------------------------------------------------------------
__global__ __launch_bounds__(256) void gemm_out_k(
    const us* __restrict__ X, const float* __restrict__ W,
    const float* __restrict__ bias, float* __restrict__ Y, int N) {
    __shared__ float Ws[128 * 32];
    __shared__ float Xs[8][128];
    const int tid = threadIdx.x;
    const int row0 = blockIdx.x * 8;
    #pragma unroll
    for (int it = 0; it < 16; ++it) Ws[it * 256 + tid] = W[it * 256 + tid];
    #pragma unroll
    for (int it = 0; it < 2; ++it) {
        int idx = it * 256 + tid;
        int rr = idx >> 6, kp = idx & 63;
        int gr = row0 + rr;
        unsigned u = (gr < N) ? *(const unsigned*)(X + (size_t)gr * 128 + kp * 2) : 0u;
        Xs[rr][kp * 2]     = bflo(u);
        Xs[rr][kp * 2 + 1] = bfhi(u);
    }
    __syncthreads();
    const int rr = tid >> 5, c = tid & 31;
    float acc = bias[c];
    #pragma unroll 8
    for (int k = 0; k < 128; ++k)
        acc = fmaf(Xs[rr][k], Ws[k * 32 + c], acc);
    int gr = row0 + rr;
    if (gr < N) Y[(size_t)gr * 32 + c] = acc;
}

// ---------------------------------------------------------------------------
// Edge aggregation, both edge types, degree-sorted via perm. 16 lanes per
// dst (4 dsts/wave); lane li owns dims [li*8, li*8+8); per-head dot via one
// shfl_xor. k/v gathers software-pipelined one edge ahead. gelu fused.
// ---------------------------------------------------------------------------
__global__ __launch_bounds__(256) void edge_agg2(
    const us* __restrict__ qf, const us* __restrict__ qd,
    const us* __restrict__ ktf, const us* __restrict__ ktd,
    const us* __restrict__ vtf, const us* __restrict__ vtd,
    const int* __restrict__ rs, const int* __restrict__ esrc,
    const int* __restrict__ perm,
    us* __restrict__ aggf, us* __restrict__ aggd) {
    int gi = (blockIdx.x * 256 + threadIdx.x) >> 4;
    int li = threadIdx.x & 15;
    if (gi >= NT) return;
    int g = perm[gi];
    const us *q, *kt, *vt; us* agg; int dst;
    if (g < NF) { dst = g;      q = qf; kt = ktd; vt = vtd; agg = aggf; }
    else        { dst = g - NF; q = qd; kt = ktf; vt = vtf; agg = aggd; }

    uint4 qb = *(const uint4*)(q + (size_t)dst * 128 + li * 8);
    float qv[8];
    qv[0] = bflo(qb.x); qv[1] = bfhi(qb.x);
    qv[2] = bflo(qb.y); qv[3] = bfhi(qb.y);
    qv[4] = bflo(qb.z); qv[5] = bfhi(qb.z);
    qv[6] = bflo(qb.w); qv[7] = bfhi(qb.w);

    int p0 = rs[g], p1 = rs[g + 1];
    float m = -INFINITY, s = 0.f;
    float a[8];
    #pragma unroll
    for (int j = 0; j < 8; ++j) a[j] = 0.f;

    uint4 kb, vb;
    if (p0 < p1) {
        int s0 = esrc[p0];
        kb = *(const uint4*)(kt + (size_t)s0 * 128 + li * 8);
        vb = *(const uint4*)(vt + (size_t)s0 * 128 + li * 8);
    }
    for (int p = p0; p < p1; ++p) {
        uint4 kc = kb, vc = vb;
        if (p + 1 < p1) {
            int sn = esrc[p + 1];
            kb = *(const uint4*)(kt + (size_t)sn * 128 + li * 8);
            vb = *(const uint4*)(vt + (size_t)sn * 128 + li * 8);
        }
        float part = qv[0] * bflo(kc.x);
        part = fmaf(qv[1], bfhi(kc.x), part);
        part = fmaf(qv[2], bflo(kc.y), part);
        part = fmaf(qv[3], bfhi(kc.y), part);
        part = fmaf(qv[4], bflo(kc.z), part);
        part = fmaf(qv[5], bfhi(kc.z), part);
        part = fmaf(qv[6], bflo(kc.w), part);
        part = fmaf(qv[7], bfhi(kc.w), part);
        part += __shfl_xor(part, 1);            // full 16-dim head dot
        float mn = fmaxf(m, part);
        float fac = __expf(m - mn);             // m=-inf first edge -> fac=0
        float w = __expf(part - mn);
        s = s * fac + w;
        float vf[8];
        vf[0] = bflo(vc.x); vf[1] = bfhi(vc.x);
        vf[2] = bflo(vc.y); vf[3] = bfhi(vc.y);
        vf[4] = bflo(vc.z); vf[5] = bfhi(vc.z);
        vf[6] = bflo(vc.w); vf[7] = bfhi(vc.w);
        #pragma unroll
        for (int j = 0; j < 8; ++j) a[j] = fmaf(w, vf[j], a[j] * fac);
        m = mn;
    }
    float r = 1.0f / (s + 1e-16f);
    unsigned o[4];
    #pragma unroll
    for (int j = 0; j < 4; ++j) {
        us lo = f2bf(gelu_f(a[2 * j] * r));
        us hi = f2bf(gelu_f(a[2 * j + 1] * r));
        o[j] = (unsigned)lo | ((unsigned)hi << 16);
    }
    *(uint4*)(agg + (size_t)dst * 128 + li * 8) = make_uint4(o[0], o[1], o[2], o[3]);
}

// ---------------------------------------------------------------------------
// CSR build over the COMBINED dst space (feature dsts [0,NF), device [NF,NT)).
// ---------------------------------------------------------------------------
__global__ void k_count2(const int* __restrict__ dA, const int* __restrict__ dB,
                         int* __restrict__ cnt) {
    int i = blockIdx.x * 256 + threadIdx.x;
    if (i < NE) atomicAdd(&cnt[dA[i]], 1);
    else if (i < 2 * NE) atomicAdd(&cnt[NF + dB[i - NE]], 1);
}

// degree histogram (cnt holds degrees right after k_count2)
__global__ void k_hist(const int* __restrict__ cnt, int* __restrict__ hist) {
    int i = blockIdx.x * 256 + threadIdx.x;
    if (i < NT) atomicAdd(&hist[min(cnt[i], 255)], 1);
}

__global__ void k_hist_scan(const int* __restrict__ hist, int* __restrict__ binoff) {
    __shared__ int sd[256];
    int t = threadIdx.x;
    int v = hist[t];
    sd[t] = v; __syncthreads();
    for (int off = 1; off < 256; off <<= 1) {
        int add = (t >= off) ? sd[t - off] : 0;
        __syncthreads();
        sd[t] += add;
        __syncthreads();
    }
    binoff[t] = sd[t] - v;   // exclusive
}

__global__ void k_perm(const int* __restrict__ cnt, int* __restrict__ binoff,
                       int* __restrict__ perm) {
    int i = blockIdx.x * 256 + threadIdx.x;
    if (i < NT) {
        int pos = atomicAdd(&binoff[min(cnt[i], 255)], 1);
        perm[pos] = i;
    }
}

__global__ void k_scan_partial(const int* __restrict__ cnt, int* __restrict__ part, int n) {
    __shared__ int sd[256];
    int t = threadIdx.x;
    int base = blockIdx.x * 1024 + t * 4;
    int s = 0;
    #pragma unroll
    for (int j = 0; j < 4; ++j) { int i = base + j; if (i < n) s += cnt[i]; }
    sd[t] = s; __syncthreads();
    for (int off = 128; off > 0; off >>= 1) {
        if (t < off) sd[t] += sd[t + off];
        __syncthreads();
    }
    if (t == 0) part[blockIdx.x] = sd[0];
}

__global__ void k_scan_small(int* part, int nb, int* row_start, int n) {
    if (threadIdx.x == 0 && blockIdx.x == 0) {
        int run = 0;
        for (int i = 0; i < nb; ++i) { int v = part[i]; part[i] = run; run += v; }
        row_start[n] = run;
    }
}

__global__ void k_scan_final(const int* __restrict__ cnt, const int* __restrict__ part,
                             int* __restrict__ row_start, int n) {
    __shared__ int sd[256];
    int t = threadIdx.x;
    int base = blockIdx.x * 1024 + t * 4;
    int v[4]; int s = 0;
    #pragma unroll
    for (int j = 0; j < 4; ++j) { int i = base + j; v[j] = (i < n) ? cnt[i] : 0; s += v[j]; }
    sd[t] = s; __syncthreads();
    for (int off = 1; off < 256; off <<= 1) {
        int add = (t >= off) ? sd[t - off] : 0;
        __syncthreads();
        sd[t] += add;
        __syncthreads();
    }
    int excl = part[blockIdx.x] + sd[t] - s;
    #pragma unroll
    for (int j = 0; j < 4; ++j) {
        int i = base + j;
        if (i < n) row_start[i] = excl;
        excl += v[j];
    }
}

__global__ void k_copy_int(const int* __restrict__ a, int* __restrict__ b, int n) {
    int i = blockIdx.x * 256 + threadIdx.x;
    if (i < n) b[i] = a[i];
}

__global__ void k_fill2(const int* __restrict__ sA, const int* __restrict__ dA,
                        const int* __restrict__ sB, const int* __restrict__ dB,
                        int* __restrict__ cursor, int* __restrict__ esrc) {
    int i = blockIdx.x * 256 + threadIdx.x;
    if (i < NE) {
        int p = atomicAdd(&cursor[dA[i]], 1);
        esrc[p] = sA[i];
    } else if (i < 2 * NE) {
        int j = i - NE;
        int p = atomicAdd(&cursor[NF + dB[j]], 1);
        esrc[p] = sB[j];
    }
}

// ---------------------------------------------------------------------------
extern "C" void kernel_launch(void* const* d_in, const int* in_sizes, int n_in,
                              void* d_out, int out_size, void* d_ws, size_t ws_size,
                              hipStream_t stream) {
    const float* x_device = (const float*)d_in[0];
    const float* x_feature = (const float*)d_in[1];
    const int* e_df_src = (const int*)d_in[2];
    const int* e_df_dst = (const int*)d_in[3];
    const int* e_fd_src = (const int*)d_in[4];
    const int* e_fd_dst = (const int*)d_in[5];
    const float* W_dev_in = (const float*)d_in[6];
    const float* b_dev_in = (const float*)d_in[7];
    const float* W_feat_in = (const float*)d_in[8];
    const float* b_feat_in = (const float*)d_in[9];
    const float* Wk = (const float*)d_in[10];
    const float* bk = (const float*)d_in[11];
    const float* Wq = (const float*)d_in[12];
    const float* bq = (const float*)d_in[13];
    const float* Wv = (const float*)d_in[14];
    const float* bv = (const float*)d_in[15];
    const float* a_rel = (const float*)d_in[16];
    const float* m_rel = (const float*)d_in[17];
    const float* p_rel = (const float*)d_in[18];
    const float* Wa = (const float*)d_in[19];
    const float* ba = (const float*)d_in[20];
    const float* skip = (const float*)d_in[21];
    const float* ln_g = (const float*)d_in[22];
    const float* ln_b = (const float*)d_in[23];
    const float* W_out = (const float*)d_in[24];
    const float* b_out = (const float*)d_in[25];

    char* ws = (char*)d_ws;
    size_t off = 0;
    auto alloc = [&](size_t bytes) -> void* {
        void* p = ws + off;
        off = (off + bytes + 255) & ~(size_t)255;
        return p;
    };
    us* xd     = (us*)alloc((size_t)ND * 128 * 2);
    us* xf     = (us*)alloc((size_t)NF * 128 * 2);
    us* qkv_d  = (us*)alloc((size_t)3 * ND * 128 * 2);
    us* qkv_f  = (us*)alloc((size_t)3 * NF * 128 * 2);
    us* agg_d  = (us*)alloc((size_t)ND * 128 * 2);
    us* agg_f  = (us*)alloc((size_t)NF * 128 * 2);
    us* WT     = (us*)alloc((size_t)18 * 16384 * 2);
    float* B_all = (float*)alloc(18 * 128 * 4);
    int* cnt    = (int*)alloc((size_t)NT * 4);
    int* rs     = (int*)alloc((size_t)(NT + 1) * 4);
    int* esrc   = (int*)alloc((size_t)2 * NE * 4);
    int* part   = (int*)alloc(128 * 4);
    int* hist   = (int*)alloc(256 * 4);
    int* binoff = (int*)alloc(256 * 4);
    int* perm   = (int*)alloc((size_t)NT * 4);

    // ---- combined CSR build + degree-sorted permutation
    hipMemsetAsync(cnt, 0, (size_t)NT * 4, stream);
    hipMemsetAsync(hist, 0, 256 * 4, stream);
    k_count2<<<(2 * NE + 255) / 256, 256, 0, stream>>>(e_df_dst, e_fd_dst, cnt);
    k_hist<<<(NT + 255) / 256, 256, 0, stream>>>(cnt, hist);
    k_hist_scan<<<1, 256, 0, stream>>>(hist, binoff);
    k_perm<<<(NT + 255) / 256, 256, 0, stream>>>(cnt, binoff, perm);
    int nb = (NT + 1023) / 1024;
    k_scan_partial<<<nb, 256, 0, stream>>>(cnt, part, NT);
    k_scan_small<<<1, 64, 0, stream>>>(part, nb, rs, NT);
    k_scan_final<<<nb, 256, 0, stream>>>(cnt, part, rs, NT);
    k_copy_int<<<(NT + 255) / 256, 256, 0, stream>>>(rs, cnt, NT);
    k_fill2<<<(2 * NE + 255) / 256, 256, 0, stream>>>(e_df_src, e_df_dst,
                                                      e_fd_src, e_fd_dst, cnt, esrc);

    // ---- weight/bias prep
    prep_all<<<(18 * 16384 + 18 * 128 + 255) / 256, 256, 0, stream>>>(
        W_dev_in, W_feat_in, Wq, Wk, Wv, Wa,
        b_dev_in, b_feat_in, bq, bk, bv, ba,
        a_rel, m_rel, p_rel, WT, B_all);

    const int GBD = (ND + 127) / 128, GBF = (NF + 127) / 128;

    // ---- input projections + relu (fp32 in, bf16 out), both types fused
    mfma_gemm2<1, 1, 0><<<dim3(GBD + GBF, 1), 256, 0, stream>>>(
        x_device, x_feature, WT, B_all, xd, xf, ND, NF, GBD, 0,
        nullptr, nullptr, nullptr, nullptr, nullptr);

    for (int l = 0; l < 2; ++l) {
        // fused q/k/v for both types: ids q=2+lt, k=6+lt, v=10+lt
        mfma_gemm2<0, 0, 0><<<dim3(GBD + GBF, 3), 256, 0, stream>>>(
            xd, xf, WT, B_all, qkv_d, qkv_f, ND, NF, GBD, 2 + l * 2,
            nullptr, nullptr, nullptr, nullptr, nullptr);

        // both edge types in one dispatch, degree-sorted
        edge_agg2<<<((NT * 16) + 255) / 256, 256, 0, stream>>>(
            qkv_f, qkv_d,
            qkv_f + (size_t)NF * 128, qkv_d + (size_t)ND * 128,
            qkv_f + (size_t)2 * NF * 128, qkv_d + (size_t)2 * ND * 128,
            rs, esrc, perm, agg_f, agg_d);

        // o = gelu(agg) @ Wa + ba, fused skip+residual+LN, in place on x
        mfma_gemm2<0, 0, 1><<<dim3(GBD + GBF, 1), 256, 0, stream>>>(
            agg_d, agg_f, WT, B_all, nullptr, nullptr, ND, NF, GBD, 14 + l * 2,
            xd, xf, skip, ln_g, ln_b);
    }

    gemm_out_k<<<(ND + 7) / 8, 256, 0, stream>>>(xd, W_out, b_out, (float*)d_out, ND);
}

// Round 5
// 391.911 us; speedup vs baseline: 2.0513x; 2.0513x over previous
//
#include <hip/hip_runtime.h>
#include <math.h>

#define ND 20000
#define NF 50000
#define NE 400000
#define NT (NF + ND)     // combined dst nodes (feature first, then device)
// HID=128, H=8, D=16, L=2, IN=128, OUT=32

typedef __attribute__((ext_vector_type(8))) short short8;
typedef __attribute__((ext_vector_type(4))) float f32x4;
typedef unsigned short us;

static __device__ __forceinline__ us f2bf(float f) {
    unsigned u = __builtin_bit_cast(unsigned, f);
    u += 0x7FFF + ((u >> 16) & 1);          // round-to-nearest-even
    return (us)(u >> 16);
}
static __device__ __forceinline__ float bf2f(us h) {
    return __builtin_bit_cast(float, (unsigned)h << 16);
}
static __device__ __forceinline__ float bflo(unsigned u) {
    return __builtin_bit_cast(float, u << 16);
}
static __device__ __forceinline__ float bfhi(unsigned u) {
    return __builtin_bit_cast(float, u & 0xFFFF0000u);
}
static __device__ __forceinline__ float gelu_f(float x) {
    return 0.5f * x * (1.0f + erff(x * 0.70710678118654752f));
}

// ---------------------------------------------------------------------------
// Weight+bias prep. WT[id][c][k] (bf16, pre-transposed), B_all[id][128] fp32.
// id 0: W_dev_in, 1: W_feat_in, 2+lt: Wq, 6+lt: WkF (a_rel & p_rel/4 folded),
// 10+lt: WvF (m_rel folded), 14+lt: Wa.   lt = l*2+t.
// ---------------------------------------------------------------------------
__global__ void prep_all(const float* __restrict__ W_dev_in, const float* __restrict__ W_feat_in,
                         const float* __restrict__ Wq, const float* __restrict__ Wk,
                         const float* __restrict__ Wv, const float* __restrict__ Wa,
                         const float* __restrict__ b_dev_in, const float* __restrict__ b_feat_in,
                         const float* __restrict__ bq, const float* __restrict__ bk,
                         const float* __restrict__ bv, const float* __restrict__ ba,
                         const float* __restrict__ a_rel, const float* __restrict__ m_rel,
                         const float* __restrict__ p_rel,
                         us* __restrict__ WT, float* __restrict__ B_all) {
    int idx = blockIdx.x * 256 + threadIdx.x;
    if (idx < 18 * 16384) {
        int k = idx & 127, c = (idx >> 7) & 127, id = idx >> 14;
        float val;
        if (id == 0) val = W_dev_in[k * 128 + c];
        else if (id == 1) val = W_feat_in[k * 128 + c];
        else if (id < 6) val = Wq[(id - 2) * 16384 + k * 128 + c];
        else if (id < 10) {
            int lt = id - 6, h = c >> 4, e = c & 15;
            const float* A = a_rel + (lt * 8 + h) * 256;
            const float* Ws = Wk + lt * 16384 + k * 128 + h * 16;
            float sm = 0.f;
            #pragma unroll
            for (int d = 0; d < 16; ++d) sm += Ws[d] * A[d * 16 + e];
            val = sm * p_rel[lt * 8 + h] * 0.25f;
        } else if (id < 14) {
            int lt = id - 10, h = c >> 4, e = c & 15;
            const float* A = m_rel + (lt * 8 + h) * 256;
            const float* Ws = Wv + lt * 16384 + k * 128 + h * 16;
            float sm = 0.f;
            #pragma unroll
            for (int d = 0; d < 16; ++d) sm += Ws[d] * A[d * 16 + e];
            val = sm;
        } else val = Wa[(id - 14) * 16384 + k * 128 + c];
        WT[(size_t)id * 16384 + c * 128 + k] = f2bf(val);
    } else {
        int j = idx - 18 * 16384;
        if (j >= 18 * 128) return;
        int c = j & 127, id = j >> 7;
        float v;
        if (id == 0) v = b_dev_in[c];
        else if (id == 1) v = b_feat_in[c];
        else if (id < 6) v = bq[(id - 2) * 128 + c];
        else if (id < 10) {
            int lt = id - 6, h = c >> 4, e = c & 15;
            const float* A = a_rel + (lt * 8 + h) * 256;
            const float* bs = bk + lt * 128 + h * 16;
            float sm = 0.f;
            #pragma unroll
            for (int d = 0; d < 16; ++d) sm += bs[d] * A[d * 16 + e];
            v = sm * p_rel[lt * 8 + h] * 0.25f;
        } else if (id < 14) {
            int lt = id - 10, h = c >> 4, e = c & 15;
            const float* A = m_rel + (lt * 8 + h) * 256;
            const float* bs = bv + lt * 128 + h * 16;
            float sm = 0.f;
            #pragma unroll
            for (int d = 0; d < 16; ++d) sm += bs[d] * A[d * 16 + e];
            v = sm;
        } else v = ba[(id - 14) * 128 + c];
        B_all[j] = v;
    }
}

// ---------------------------------------------------------------------------
// MFMA GEMM over BOTH node types in one dispatch. blockIdx.x < GB0 -> type 0
// (device), else type 1 (feature). blockIdx.y = output plane (q/k/v).
// Weight id = widbase + type + 4*blockIdx.y.
// LNF=1: skip Y store; instead t = x + sk*o + (1-sk)*x, x = LN(t)*g + b
// written in place to the x buffer (row lives in one 16-lane shfl group).
// ---------------------------------------------------------------------------
template<int AF32, int RELU, int LNF>
__global__ __launch_bounds__(256) void mfma_gemm2(
    const void* __restrict__ X0, const void* __restrict__ X1,
    const us* __restrict__ WT0, const float* __restrict__ Ball,
    us* __restrict__ Y0, us* __restrict__ Y1,
    int N0, int N1, int GB0, int widbase,
    us* __restrict__ X0w, us* __restrict__ X1w,
    const float* __restrict__ skipv, const float* __restrict__ lng,
    const float* __restrict__ lnb) {
    const int type = (blockIdx.x >= (unsigned)GB0) ? 1 : 0;
    const int bx = blockIdx.x - (type ? GB0 : 0);
    const int N = type ? N1 : N0;
    const void* Xv = type ? X1 : X0;
    const int wid = widbase + type + 4 * blockIdx.y;
    const us* WT = WT0 + (size_t)wid * 16384;
    const float* bias = Ball + wid * 128;

    const int lane = threadIdx.x & 63;
    const int wave = threadIdx.x >> 6;
    const int row_base = bx * 128 + wave * 32;
    const int l15 = lane & 15, lg = lane >> 4;
    const int kbase = lg * 8;

    short8 a[2][4];
    #pragma unroll
    for (int mf = 0; mf < 2; ++mf) {
        int r = row_base + mf * 16 + l15;
        r = r < N ? r : N - 1;
        if (AF32) {
            const float* Xf = (const float*)Xv + (size_t)r * 128;
            #pragma unroll
            for (int kf = 0; kf < 4; ++kf) {
                float4 lo = *(const float4*)(Xf + kf * 32 + kbase);
                float4 hi = *(const float4*)(Xf + kf * 32 + kbase + 4);
                short8 t;
                t[0] = (short)f2bf(lo.x); t[1] = (short)f2bf(lo.y);
                t[2] = (short)f2bf(lo.z); t[3] = (short)f2bf(lo.w);
                t[4] = (short)f2bf(hi.x); t[5] = (short)f2bf(hi.y);
                t[6] = (short)f2bf(hi.z); t[7] = (short)f2bf(hi.w);
                a[mf][kf] = t;
            }
        } else {
            const us* Xb = (const us*)Xv + (size_t)r * 128;
            #pragma unroll
            for (int kf = 0; kf < 4; ++kf)
                a[mf][kf] = *(const short8*)(Xb + kf * 32 + kbase);
        }
    }

    f32x4 acc[2][8];
    #pragma unroll
    for (int mf = 0; mf < 2; ++mf)
        #pragma unroll
        for (int cf = 0; cf < 8; ++cf) acc[mf][cf] = (f32x4){0.f, 0.f, 0.f, 0.f};

    #pragma unroll
    for (int cf = 0; cf < 8; ++cf) {
        #pragma unroll
        for (int kf = 0; kf < 4; ++kf) {
            short8 b = *(const short8*)(WT + (size_t)(cf * 16 + l15) * 128 + kf * 32 + kbase);
            acc[0][cf] = __builtin_amdgcn_mfma_f32_16x16x32_bf16(a[0][kf], b, acc[0][cf], 0, 0, 0);
            acc[1][cf] = __builtin_amdgcn_mfma_f32_16x16x32_bf16(a[1][kf], b, acc[1][cf], 0, 0, 0);
        }
    }

    float bval[8];
    #pragma unroll
    for (int cf = 0; cf < 8; ++cf) bval[cf] = bias[cf * 16 + l15];

    if (LNF) {
        const int lt = widbase - 14 + type;     // = l*2 + type
        float sk = 1.f / (1.f + __expf(-skipv[lt]));
        float gv[8], bv2[8];
        #pragma unroll
        for (int cf = 0; cf < 8; ++cf) {
            gv[cf]  = lng[(size_t)lt * 128 + cf * 16 + l15];
            bv2[cf] = lnb[(size_t)lt * 128 + cf * 16 + l15];
        }
        us* xw = type ? X1w : X0w;
        #pragma unroll
        for (int mf = 0; mf < 2; ++mf)
            #pragma unroll
            for (int r = 0; r < 4; ++r) {
                int grow = row_base + mf * 16 + lg * 4 + r;   // uniform in shfl-16 group
                if (grow >= N) continue;
                float t[8];
                float sum = 0.f;
                #pragma unroll
                for (int cf = 0; cf < 8; ++cf) {
                    float o = acc[mf][cf][r] + bval[cf];
                    float x = bf2f(xw[(size_t)grow * 128 + cf * 16 + l15]);
                    t[cf] = (2.f - sk) * x + sk * o;
                    sum += t[cf];
                }
                sum += __shfl_xor(sum, 1); sum += __shfl_xor(sum, 2);
                sum += __shfl_xor(sum, 4); sum += __shfl_xor(sum, 8);
                float mean = sum * (1.0f / 128.0f);
                float vs = 0.f;
                #pragma unroll
                for (int cf = 0; cf < 8; ++cf) { t[cf] -= mean; vs += t[cf] * t[cf]; }
                vs += __shfl_xor(vs, 1); vs += __shfl_xor(vs, 2);
                vs += __shfl_xor(vs, 4); vs += __shfl_xor(vs, 8);
                float inv = rsqrtf(vs * (1.0f / 128.0f) + 1e-5f);
                #pragma unroll
                for (int cf = 0; cf < 8; ++cf)
                    xw[(size_t)grow * 128 + cf * 16 + l15] = f2bf(t[cf] * inv * gv[cf] + bv2[cf]);
            }
        return;
    }

    us* Yp = (type ? Y1 : Y0) + (size_t)blockIdx.y * N * 128;
    #pragma unroll
    for (int mf = 0; mf < 2; ++mf)
        #pragma unroll
        for (int r = 0; r < 4; ++r) {
            int grow = row_base + mf * 16 + lg * 4 + r;
            if (grow >= N) continue;
            #pragma unroll
            for (int cf = 0; cf < 8; ++cf) {
                float v = acc[mf][cf][r] + bval[cf];
                if (RELU) v = fmaxf(v, 0.f);
                Yp[(size_t)grow * 128 + cf * 16 + l15] = f2bf(v);
            }
        }
}

// ---------------------------------------------------------------------------
// Final head: Y[N,32](f32) = X(bf16)[N,128] @ W[128,32] + b
// ---------------------------------------------------------------------------
__global__ __launch_bounds__(256) void gemm_out_k(
    const us* __restrict__ X, const float* __restrict__ W,
    const float* __restrict__ bias, float* __restrict__ Y, int N) {
    __shared__ float Ws[128 * 32];
    __shared__ float Xs[8][128];
    const int tid = threadIdx.x;
    const int row0 = blockIdx.x * 8;
    #pragma unroll
    for (int it = 0; it < 16; ++it) Ws[it * 256 + tid] = W[it * 256 + tid];
    #pragma unroll
    for (int it = 0; it < 2; ++it) {
        int idx = it * 256 + tid;
        int rr = idx >> 6, kp = idx & 63;
        int gr = row0 + rr;
        unsigned u = (gr < N) ? *(const unsigned*)(X + (size_t)gr * 128 + kp * 2) : 0u;
        Xs[rr][kp * 2]     = bflo(u);
        Xs[rr][kp * 2 + 1] = bfhi(u);
    }
    __syncthreads();
    const int rr = tid >> 5, c = tid & 31;
    float acc = bias[c];
    #pragma unroll 8
    for (int k = 0; k < 128; ++k)
        acc = fmaf(Xs[rr][k], Ws[k * 32 + c], acc);
    int gr = row0 + rr;
    if (gr < N) Y[(size_t)gr * 32 + c] = acc;
}

// ---------------------------------------------------------------------------
// Edge aggregation, both edge types in one dispatch. 16 lanes per dst
// (4 dsts/wave); lane li owns dims [li*8, li*8+8); per-head dot via one
// shfl_xor. NO-MAX softmax: logits are LN-bounded (|l| << 80), so
// exp(l)/sum(exp(l)) is computed directly -- removes the serial online-max
// rescale chain; loop body is independent FMA accumulation, fully pipelined.
// k/v gathers prefetched one edge ahead. gelu fused into epilogue.
// ---------------------------------------------------------------------------
__global__ __launch_bounds__(256) void edge_agg2(
    const us* __restrict__ qf, const us* __restrict__ qd,
    const us* __restrict__ ktf, const us* __restrict__ ktd,
    const us* __restrict__ vtf, const us* __restrict__ vtd,
    const int* __restrict__ rs, const int* __restrict__ esrc,
    us* __restrict__ aggf, us* __restrict__ aggd) {
    int g = (blockIdx.x * 256 + threadIdx.x) >> 4;
    int li = threadIdx.x & 15;
    if (g >= NT) return;
    const us *q, *kt, *vt; us* agg; int dst;
    if (g < NF) { dst = g;      q = qf; kt = ktd; vt = vtd; agg = aggf; }
    else        { dst = g - NF; q = qd; kt = ktf; vt = vtf; agg = aggf == aggf ? aggd : aggd; }

    uint4 qb = *(const uint4*)(q + (size_t)dst * 128 + li * 8);
    float qv[8];
    qv[0] = bflo(qb.x); qv[1] = bfhi(qb.x);
    qv[2] = bflo(qb.y); qv[3] = bfhi(qb.y);
    qv[4] = bflo(qb.z); qv[5] = bfhi(qb.z);
    qv[6] = bflo(qb.w); qv[7] = bfhi(qb.w);

    int p0 = rs[g], p1 = rs[g + 1];
    float s = 0.f;
    float a[8];
    #pragma unroll
    for (int j = 0; j < 8; ++j) a[j] = 0.f;

    uint4 kb, vb;
    if (p0 < p1) {
        int s0 = esrc[p0];
        kb = *(const uint4*)(kt + (size_t)s0 * 128 + li * 8);
        vb = *(const uint4*)(vt + (size_t)s0 * 128 + li * 8);
    }
    for (int p = p0; p < p1; ++p) {
        uint4 kc = kb, vc = vb;
        if (p + 1 < p1) {
            int sn = esrc[p + 1];
            kb = *(const uint4*)(kt + (size_t)sn * 128 + li * 8);
            vb = *(const uint4*)(vt + (size_t)sn * 128 + li * 8);
        }
        float part = qv[0] * bflo(kc.x);
        part = fmaf(qv[1], bfhi(kc.x), part);
        part = fmaf(qv[2], bflo(kc.y), part);
        part = fmaf(qv[3], bfhi(kc.y), part);
        part = fmaf(qv[4], bflo(kc.z), part);
        part = fmaf(qv[5], bfhi(kc.z), part);
        part = fmaf(qv[6], bflo(kc.w), part);
        part = fmaf(qv[7], bfhi(kc.w), part);
        part += __shfl_xor(part, 1);            // full 16-dim head dot
        float w = __expf(part);                 // no max-shift (bounded logits)
        s += w;
        a[0] = fmaf(w, bflo(vc.x), a[0]);
        a[1] = fmaf(w, bfhi(vc.x), a[1]);
        a[2] = fmaf(w, bflo(vc.y), a[2]);
        a[3] = fmaf(w, bfhi(vc.y), a[3]);
        a[4] = fmaf(w, bflo(vc.z), a[4]);
        a[5] = fmaf(w, bfhi(vc.z), a[5]);
        a[6] = fmaf(w, bflo(vc.w), a[6]);
        a[7] = fmaf(w, bfhi(vc.w), a[7]);
    }
    float r = 1.0f / (s + 1e-16f);
    unsigned o[4];
    #pragma unroll
    for (int j = 0; j < 4; ++j) {
        us lo = f2bf(gelu_f(a[2 * j] * r));
        us hi = f2bf(gelu_f(a[2 * j + 1] * r));
        o[j] = (unsigned)lo | ((unsigned)hi << 16);
    }
    *(uint4*)(agg + (size_t)dst * 128 + li * 8) = make_uint4(o[0], o[1], o[2], o[3]);
}

// ---------------------------------------------------------------------------
// CSR build over the COMBINED dst space (feature dsts [0,NF), device [NF,NT)).
// ---------------------------------------------------------------------------
__global__ void k_count2(const int* __restrict__ dA, const int* __restrict__ dB,
                         int* __restrict__ cnt) {
    int i = blockIdx.x * 256 + threadIdx.x;
    if (i < NE) atomicAdd(&cnt[dA[i]], 1);
    else if (i < 2 * NE) atomicAdd(&cnt[NF + dB[i - NE]], 1);
}

__global__ void k_scan_partial(const int* __restrict__ cnt, int* __restrict__ part, int n) {
    __shared__ int sd[256];
    int t = threadIdx.x;
    int base = blockIdx.x * 1024 + t * 4;
    int s = 0;
    #pragma unroll
    for (int j = 0; j < 4; ++j) { int i = base + j; if (i < n) s += cnt[i]; }
    sd[t] = s; __syncthreads();
    for (int off = 128; off > 0; off >>= 1) {
        if (t < off) sd[t] += sd[t + off];
        __syncthreads();
    }
    if (t == 0) part[blockIdx.x] = sd[0];
}

__global__ void k_scan_small(int* part, int nb, int* row_start, int n) {
    if (threadIdx.x == 0 && blockIdx.x == 0) {
        int run = 0;
        for (int i = 0; i < nb; ++i) { int v = part[i]; part[i] = run; run += v; }
        row_start[n] = run;
    }
}

__global__ void k_scan_final(const int* __restrict__ cnt, const int* __restrict__ part,
                             int* __restrict__ row_start, int n) {
    __shared__ int sd[256];
    int t = threadIdx.x;
    int base = blockIdx.x * 1024 + t * 4;
    int v[4]; int s = 0;
    #pragma unroll
    for (int j = 0; j < 4; ++j) { int i = base + j; v[j] = (i < n) ? cnt[i] : 0; s += v[j]; }
    sd[t] = s; __syncthreads();
    for (int off = 1; off < 256; off <<= 1) {
        int add = (t >= off) ? sd[t - off] : 0;
        __syncthreads();
        sd[t] += add;
        __syncthreads();
    }
    int excl = part[blockIdx.x] + sd[t] - s;
    #pragma unroll
    for (int j = 0; j < 4; ++j) {
        int i = base + j;
        if (i < n) row_start[i] = excl;
        excl += v[j];
    }
}

__global__ void k_copy_int(const int* __restrict__ a, int* __restrict__ b, int n) {
    int i = blockIdx.x * 256 + threadIdx.x;
    if (i < n) b[i] = a[i];
}

__global__ void k_fill2(const int* __restrict__ sA, const int* __restrict__ dA,
                        const int* __restrict__ sB, const int* __restrict__ dB,
                        int* __restrict__ cursor, int* __restrict__ esrc) {
    int i = blockIdx.x * 256 + threadIdx.x;
    if (i < NE) {
        int p = atomicAdd(&cursor[dA[i]], 1);
        esrc[p] = sA[i];
    } else if (i < 2 * NE) {
        int j = i - NE;
        int p = atomicAdd(&cursor[NF + dB[j]], 1);
        esrc[p] = sB[j];
    }
}

// ---------------------------------------------------------------------------
extern "C" void kernel_launch(void* const* d_in, const int* in_sizes, int n_in,
                              void* d_out, int out_size, void* d_ws, size_t ws_size,
                              hipStream_t stream) {
    const float* x_device = (const float*)d_in[0];
    const float* x_feature = (const float*)d_in[1];
    const int* e_df_src = (const int*)d_in[2];
    const int* e_df_dst = (const int*)d_in[3];
    const int* e_fd_src = (const int*)d_in[4];
    const int* e_fd_dst = (const int*)d_in[5];
    const float* W_dev_in = (const float*)d_in[6];
    const float* b_dev_in = (const float*)d_in[7];
    const float* W_feat_in = (const float*)d_in[8];
    const float* b_feat_in = (const float*)d_in[9];
    const float* Wk = (const float*)d_in[10];
    const float* bk = (const float*)d_in[11];
    const float* Wq = (const float*)d_in[12];
    const float* bq = (const float*)d_in[13];
    const float* Wv = (const float*)d_in[14];
    const float* bv = (const float*)d_in[15];
    const float* a_rel = (const float*)d_in[16];
    const float* m_rel = (const float*)d_in[17];
    const float* p_rel = (const float*)d_in[18];
    const float* Wa = (const float*)d_in[19];
    const float* ba = (const float*)d_in[20];
    const float* skip = (const float*)d_in[21];
    const float* ln_g = (const float*)d_in[22];
    const float* ln_b = (const float*)d_in[23];
    const float* W_out = (const float*)d_in[24];
    const float* b_out = (const float*)d_in[25];

    char* ws = (char*)d_ws;
    size_t off = 0;
    auto alloc = [&](size_t bytes) -> void* {
        void* p = ws + off;
        off = (off + bytes + 255) & ~(size_t)255;
        return p;
    };
    us* xd     = (us*)alloc((size_t)ND * 128 * 2);
    us* xf     = (us*)alloc((size_t)NF * 128 * 2);
    us* qkv_d  = (us*)alloc((size_t)3 * ND * 128 * 2);
    us* qkv_f  = (us*)alloc((size_t)3 * NF * 128 * 2);
    us* agg_d  = (us*)alloc((size_t)ND * 128 * 2);
    us* agg_f  = (us*)alloc((size_t)NF * 128 * 2);
    us* WT     = (us*)alloc((size_t)18 * 16384 * 2);
    float* B_all = (float*)alloc(18 * 128 * 4);
    int* cnt    = (int*)alloc((size_t)NT * 4);
    int* rs     = (int*)alloc((size_t)(NT + 1) * 4);
    int* esrc   = (int*)alloc((size_t)2 * NE * 4);
    int* part   = (int*)alloc(128 * 4);

    // ---- combined CSR build (feature dsts 0..NF, device dsts NF..NT)
    hipMemsetAsync(cnt, 0, (size_t)NT * 4, stream);
    k_count2<<<(2 * NE + 255) / 256, 256, 0, stream>>>(e_df_dst, e_fd_dst, cnt);
    int nb = (NT + 1023) / 1024;
    k_scan_partial<<<nb, 256, 0, stream>>>(cnt, part, NT);
    k_scan_small<<<1, 64, 0, stream>>>(part, nb, rs, NT);
    k_scan_final<<<nb, 256, 0, stream>>>(cnt, part, rs, NT);
    k_copy_int<<<(NT + 255) / 256, 256, 0, stream>>>(rs, cnt, NT);
    k_fill2<<<(2 * NE + 255) / 256, 256, 0, stream>>>(e_df_src, e_df_dst,
                                                      e_fd_src, e_fd_dst, cnt, esrc);

    // ---- weight/bias prep
    prep_all<<<(18 * 16384 + 18 * 128 + 255) / 256, 256, 0, stream>>>(
        W_dev_in, W_feat_in, Wq, Wk, Wv, Wa,
        b_dev_in, b_feat_in, bq, bk, bv, ba,
        a_rel, m_rel, p_rel, WT, B_all);

    const int GBD = (ND + 127) / 128, GBF = (NF + 127) / 128;

    // ---- input projections + relu (fp32 in, bf16 out), both types fused
    mfma_gemm2<1, 1, 0><<<dim3(GBD + GBF, 1), 256, 0, stream>>>(
        x_device, x_feature, WT, B_all, xd, xf, ND, NF, GBD, 0,
        nullptr, nullptr, nullptr, nullptr, nullptr);

    for (int l = 0; l < 2; ++l) {
        // fused q/k/v for both types: ids q=2+lt, k=6+lt, v=10+lt
        mfma_gemm2<0, 0, 0><<<dim3(GBD + GBF, 3), 256, 0, stream>>>(
            xd, xf, WT, B_all, qkv_d, qkv_f, ND, NF, GBD, 2 + l * 2,
            nullptr, nullptr, nullptr, nullptr, nullptr);

        // both edge types in one dispatch
        edge_agg2<<<((NT * 16) + 255) / 256, 256, 0, stream>>>(
            qkv_f, qkv_d,
            qkv_f + (size_t)NF * 128, qkv_d + (size_t)ND * 128,
            qkv_f + (size_t)2 * NF * 128, qkv_d + (size_t)2 * ND * 128,
            rs, esrc, agg_f, agg_d);

        // o = gelu(agg) @ Wa + ba, fused skip+residual+LN, in place on x
        mfma_gemm2<0, 0, 1><<<dim3(GBD + GBF, 1), 256, 0, stream>>>(
            agg_d, agg_f, WT, B_all, nullptr, nullptr, ND, NF, GBD, 14 + l * 2,
            xd, xf, skip, ln_g, ln_b);
    }

    gemm_out_k<<<(ND + 7) / 8, 256, 0, stream>>>(xd, W_out, b_out, (float*)d_out, ND);
}

// Round 6
// 381.122 us; speedup vs baseline: 2.1094x; 1.0283x over previous
//
#include <hip/hip_runtime.h>
#include <math.h>

#define ND 20000
#define NF 50000
#define NE 400000
#define NT (NF + ND)     // combined dst nodes (feature first, then device)
// HID=128, H=8, D=16, L=2, IN=128, OUT=32

typedef __attribute__((ext_vector_type(8))) short short8;
typedef __attribute__((ext_vector_type(4))) float f32x4;
typedef unsigned short us;

static __device__ __forceinline__ us f2bf(float f) {
    unsigned u = __builtin_bit_cast(unsigned, f);
    u += 0x7FFF + ((u >> 16) & 1);          // round-to-nearest-even
    return (us)(u >> 16);
}
static __device__ __forceinline__ float bf2f(us h) {
    return __builtin_bit_cast(float, (unsigned)h << 16);
}
static __device__ __forceinline__ float bflo(unsigned u) {
    return __builtin_bit_cast(float, u << 16);
}
static __device__ __forceinline__ float bfhi(unsigned u) {
    return __builtin_bit_cast(float, u & 0xFFFF0000u);
}
static __device__ __forceinline__ float gelu_f(float x) {
    return 0.5f * x * (1.0f + erff(x * 0.70710678118654752f));
}

// ---------------------------------------------------------------------------
// Weight+bias prep. WT[id][c][k] (bf16, pre-transposed), B_all[id][128] fp32.
// id 0: W_dev_in, 1: W_feat_in, 2+lt: Wq, 6+lt: WkF (a_rel & p_rel/4 folded),
// 10+lt: WvF (m_rel folded), 14+lt: Wa.   lt = l*2+t.
// ---------------------------------------------------------------------------
__global__ void prep_all(const float* __restrict__ W_dev_in, const float* __restrict__ W_feat_in,
                         const float* __restrict__ Wq, const float* __restrict__ Wk,
                         const float* __restrict__ Wv, const float* __restrict__ Wa,
                         const float* __restrict__ b_dev_in, const float* __restrict__ b_feat_in,
                         const float* __restrict__ bq, const float* __restrict__ bk,
                         const float* __restrict__ bv, const float* __restrict__ ba,
                         const float* __restrict__ a_rel, const float* __restrict__ m_rel,
                         const float* __restrict__ p_rel,
                         us* __restrict__ WT, float* __restrict__ B_all) {
    int idx = blockIdx.x * 256 + threadIdx.x;
    if (idx < 18 * 16384) {
        int k = idx & 127, c = (idx >> 7) & 127, id = idx >> 14;
        float val;
        if (id == 0) val = W_dev_in[k * 128 + c];
        else if (id == 1) val = W_feat_in[k * 128 + c];
        else if (id < 6) val = Wq[(id - 2) * 16384 + k * 128 + c];
        else if (id < 10) {
            int lt = id - 6, h = c >> 4, e = c & 15;
            const float* A = a_rel + (lt * 8 + h) * 256;
            const float* Ws = Wk + lt * 16384 + k * 128 + h * 16;
            float sm = 0.f;
            #pragma unroll
            for (int d = 0; d < 16; ++d) sm += Ws[d] * A[d * 16 + e];
            val = sm * p_rel[lt * 8 + h] * 0.25f;
        } else if (id < 14) {
            int lt = id - 10, h = c >> 4, e = c & 15;
            const float* A = m_rel + (lt * 8 + h) * 256;
            const float* Ws = Wv + lt * 16384 + k * 128 + h * 16;
            float sm = 0.f;
            #pragma unroll
            for (int d = 0; d < 16; ++d) sm += Ws[d] * A[d * 16 + e];
            val = sm;
        } else val = Wa[(id - 14) * 16384 + k * 128 + c];
        WT[(size_t)id * 16384 + c * 128 + k] = f2bf(val);
    } else {
        int j = idx - 18 * 16384;
        if (j >= 18 * 128) return;
        int c = j & 127, id = j >> 7;
        float v;
        if (id == 0) v = b_dev_in[c];
        else if (id == 1) v = b_feat_in[c];
        else if (id < 6) v = bq[(id - 2) * 128 + c];
        else if (id < 10) {
            int lt = id - 6, h = c >> 4, e = c & 15;
            const float* A = a_rel + (lt * 8 + h) * 256;
            const float* bs = bk + lt * 128 + h * 16;
            float sm = 0.f;
            #pragma unroll
            for (int d = 0; d < 16; ++d) sm += bs[d] * A[d * 16 + e];
            v = sm * p_rel[lt * 8 + h] * 0.25f;
        } else if (id < 14) {
            int lt = id - 10, h = c >> 4, e = c & 15;
            const float* A = m_rel + (lt * 8 + h) * 256;
            const float* bs = bv + lt * 128 + h * 16;
            float sm = 0.f;
            #pragma unroll
            for (int d = 0; d < 16; ++d) sm += bs[d] * A[d * 16 + e];
            v = sm;
        } else v = ba[(id - 14) * 128 + c];
        B_all[j] = v;
    }
}

// ---------------------------------------------------------------------------
// MFMA GEMM over BOTH node types in one dispatch. blockIdx.x < GB0 -> type 0
// (device), else type 1 (feature). blockIdx.y = output plane (q/k/v).
// Weight id = widbase + type + 4*blockIdx.y.
// LNF=1: skip Y store; instead t = x + sk*o + (1-sk)*x, x = LN(t)*g + b
// written in place to the x buffer (row lives in one 16-lane shfl group).
// ---------------------------------------------------------------------------
template<int AF32, int RELU, int LNF>
__global__ __launch_bounds__(256) void mfma_gemm2(
    const void* __restrict__ X0, const void* __restrict__ X1,
    const us* __restrict__ WT0, const float* __restrict__ Ball,
    us* __restrict__ Y0, us* __restrict__ Y1,
    int N0, int N1, int GB0, int widbase,
    us* __restrict__ X0w, us* __restrict__ X1w,
    const float* __restrict__ skipv, const float* __restrict__ lng,
    const float* __restrict__ lnb) {
    const int type = (blockIdx.x >= (unsigned)GB0) ? 1 : 0;
    const int bx = blockIdx.x - (type ? GB0 : 0);
    const int N = type ? N1 : N0;
    const void* Xv = type ? X1 : X0;
    const int wid = widbase + type + 4 * blockIdx.y;
    const us* WT = WT0 + (size_t)wid * 16384;
    const float* bias = Ball + wid * 128;

    const int lane = threadIdx.x & 63;
    const int wave = threadIdx.x >> 6;
    const int row_base = bx * 128 + wave * 32;
    const int l15 = lane & 15, lg = lane >> 4;
    const int kbase = lg * 8;

    short8 a[2][4];
    #pragma unroll
    for (int mf = 0; mf < 2; ++mf) {
        int r = row_base + mf * 16 + l15;
        r = r < N ? r : N - 1;
        if (AF32) {
            const float* Xf = (const float*)Xv + (size_t)r * 128;
            #pragma unroll
            for (int kf = 0; kf < 4; ++kf) {
                float4 lo = *(const float4*)(Xf + kf * 32 + kbase);
                float4 hi = *(const float4*)(Xf + kf * 32 + kbase + 4);
                short8 t;
                t[0] = (short)f2bf(lo.x); t[1] = (short)f2bf(lo.y);
                t[2] = (short)f2bf(lo.z); t[3] = (short)f2bf(lo.w);
                t[4] = (short)f2bf(hi.x); t[5] = (short)f2bf(hi.y);
                t[6] = (short)f2bf(hi.z); t[7] = (short)f2bf(hi.w);
                a[mf][kf] = t;
            }
        } else {
            const us* Xb = (const us*)Xv + (size_t)r * 128;
            #pragma unroll
            for (int kf = 0; kf < 4; ++kf)
                a[mf][kf] = *(const short8*)(Xb + kf * 32 + kbase);
        }
    }

    f32x4 acc[2][8];
    #pragma unroll
    for (int mf = 0; mf < 2; ++mf)
        #pragma unroll
        for (int cf = 0; cf < 8; ++cf) acc[mf][cf] = (f32x4){0.f, 0.f, 0.f, 0.f};

    #pragma unroll
    for (int cf = 0; cf < 8; ++cf) {
        #pragma unroll
        for (int kf = 0; kf < 4; ++kf) {
            short8 b = *(const short8*)(WT + (size_t)(cf * 16 + l15) * 128 + kf * 32 + kbase);
            acc[0][cf] = __builtin_amdgcn_mfma_f32_16x16x32_bf16(a[0][kf], b, acc[0][cf], 0, 0, 0);
            acc[1][cf] = __builtin_amdgcn_mfma_f32_16x16x32_bf16(a[1][kf], b, acc[1][cf], 0, 0, 0);
        }
    }

    float bval[8];
    #pragma unroll
    for (int cf = 0; cf < 8; ++cf) bval[cf] = bias[cf * 16 + l15];

    if (LNF) {
        const int lt = widbase - 14 + type;     // = l*2 + type
        float sk = 1.f / (1.f + __expf(-skipv[lt]));
        float gv[8], bv2[8];
        #pragma unroll
        for (int cf = 0; cf < 8; ++cf) {
            gv[cf]  = lng[(size_t)lt * 128 + cf * 16 + l15];
            bv2[cf] = lnb[(size_t)lt * 128 + cf * 16 + l15];
        }
        us* xw = type ? X1w : X0w;
        #pragma unroll
        for (int mf = 0; mf < 2; ++mf)
            #pragma unroll
            for (int r = 0; r < 4; ++r) {
                int grow = row_base + mf * 16 + lg * 4 + r;   // uniform in shfl-16 group
                if (grow >= N) continue;
                float t[8];
                float sum = 0.f;
                #pragma unroll
                for (int cf = 0; cf < 8; ++cf) {
                    float o = acc[mf][cf][r] + bval[cf];
                    float x = bf2f(xw[(size_t)grow * 128 + cf * 16 + l15]);
                    t[cf] = (2.f - sk) * x + sk * o;
                    sum += t[cf];
                }
                sum += __shfl_xor(sum, 1); sum += __shfl_xor(sum, 2);
                sum += __shfl_xor(sum, 4); sum += __shfl_xor(sum, 8);
                float mean = sum * (1.0f / 128.0f);
                float vs = 0.f;
                #pragma unroll
                for (int cf = 0; cf < 8; ++cf) { t[cf] -= mean; vs += t[cf] * t[cf]; }
                vs += __shfl_xor(vs, 1); vs += __shfl_xor(vs, 2);
                vs += __shfl_xor(vs, 4); vs += __shfl_xor(vs, 8);
                float inv = rsqrtf(vs * (1.0f / 128.0f) + 1e-5f);
                #pragma unroll
                for (int cf = 0; cf < 8; ++cf)
                    xw[(size_t)grow * 128 + cf * 16 + l15] = f2bf(t[cf] * inv * gv[cf] + bv2[cf]);
            }
        return;
    }

    us* Yp = (type ? Y1 : Y0) + (size_t)blockIdx.y * N * 128;
    #pragma unroll
    for (int mf = 0; mf < 2; ++mf)
        #pragma unroll
        for (int r = 0; r < 4; ++r) {
            int grow = row_base + mf * 16 + lg * 4 + r;
            if (grow >= N) continue;
            #pragma unroll
            for (int cf = 0; cf < 8; ++cf) {
                float v = acc[mf][cf][r] + bval[cf];
                if (RELU) v = fmaxf(v, 0.f);
                Yp[(size_t)grow * 128 + cf * 16 + l15] = f2bf(v);
            }
        }
}

// ---------------------------------------------------------------------------
// Final head: Y[N,32](f32) = X(bf16)[N,128] @ W[128,32] + b
// ---------------------------------------------------------------------------
__global__ __launch_bounds__(256) void gemm_out_k(
    const us* __restrict__ X, const float* __restrict__ W,
    const float* __restrict__ bias, float* __restrict__ Y, int N) {
    __shared__ float Ws[128 * 32];
    __shared__ float Xs[8][128];
    const int tid = threadIdx.x;
    const int row0 = blockIdx.x * 8;
    #pragma unroll
    for (int it = 0; it < 16; ++it) Ws[it * 256 + tid] = W[it * 256 + tid];
    #pragma unroll
    for (int it = 0; it < 2; ++it) {
        int idx = it * 256 + tid;
        int rr = idx >> 6, kp = idx & 63;
        int gr = row0 + rr;
        unsigned u = (gr < N) ? *(const unsigned*)(X + (size_t)gr * 128 + kp * 2) : 0u;
        Xs[rr][kp * 2]     = bflo(u);
        Xs[rr][kp * 2 + 1] = bfhi(u);
    }
    __syncthreads();
    const int rr = tid >> 5, c = tid & 31;
    float acc = bias[c];
    #pragma unroll 8
    for (int k = 0; k < 128; ++k)
        acc = fmaf(Xs[rr][k], Ws[k * 32 + c], acc);
    int gr = row0 + rr;
    if (gr < N) Y[(size_t)gr * 32 + c] = acc;
}

// ---------------------------------------------------------------------------
// Edge aggregation, both edge types in one dispatch. 16 lanes per dst
// (4 dsts/wave); lane li owns dims [li*8, li*8+8). No-max softmax (logits
// LN-bounded). DEPTH-2x2 SOFTWARE PIPELINE: two double-buffered k/v pairs
// (A,B), esrc indices fetched a stage early, clamped loads + validity-masked
// exp so the unrolled body needs no tail code. 8 loads in flight per wave.
// ---------------------------------------------------------------------------
#define EDGE_STEP(kc, vc, pidx)                                        \
    {                                                                  \
        float part = qv[0] * bflo(kc.x);                               \
        part = fmaf(qv[1], bfhi(kc.x), part);                          \
        part = fmaf(qv[2], bflo(kc.y), part);                          \
        part = fmaf(qv[3], bfhi(kc.y), part);                          \
        part = fmaf(qv[4], bflo(kc.z), part);                          \
        part = fmaf(qv[5], bfhi(kc.z), part);                          \
        part = fmaf(qv[6], bflo(kc.w), part);                          \
        part = fmaf(qv[7], bfhi(kc.w), part);                          \
        part += __shfl_xor(part, 1);                                   \
        float w = ((pidx) < p1) ? __expf(part) : 0.f;                  \
        s += w;                                                        \
        a[0] = fmaf(w, bflo(vc.x), a[0]);                              \
        a[1] = fmaf(w, bfhi(vc.x), a[1]);                              \
        a[2] = fmaf(w, bflo(vc.y), a[2]);                              \
        a[3] = fmaf(w, bfhi(vc.y), a[3]);                              \
        a[4] = fmaf(w, bflo(vc.z), a[4]);                              \
        a[5] = fmaf(w, bfhi(vc.z), a[5]);                              \
        a[6] = fmaf(w, bflo(vc.w), a[6]);                              \
        a[7] = fmaf(w, bfhi(vc.w), a[7]);                              \
    }

__global__ __launch_bounds__(256) void edge_agg2(
    const us* __restrict__ qf, const us* __restrict__ qd,
    const us* __restrict__ ktf, const us* __restrict__ ktd,
    const us* __restrict__ vtf, const us* __restrict__ vtd,
    const int* __restrict__ rs, const int* __restrict__ esrc,
    us* __restrict__ aggf, us* __restrict__ aggd) {
    int g = (blockIdx.x * 256 + threadIdx.x) >> 4;
    int li = threadIdx.x & 15;
    if (g >= NT) return;
    const us *q, *kt, *vt; us* agg; int dst;
    if (g < NF) { dst = g;      q = qf; kt = ktd; vt = vtd; agg = aggf; }
    else        { dst = g - NF; q = qd; kt = ktf; vt = vtf; agg = aggd; }

    uint4 qb = *(const uint4*)(q + (size_t)dst * 128 + li * 8);
    float qv[8];
    qv[0] = bflo(qb.x); qv[1] = bfhi(qb.x);
    qv[2] = bflo(qb.y); qv[3] = bfhi(qb.y);
    qv[4] = bflo(qb.z); qv[5] = bfhi(qb.z);
    qv[6] = bflo(qb.w); qv[7] = bfhi(qb.w);

    const int p0 = rs[g], p1 = rs[g + 1];
    float s = 0.f;
    float a[8];
    #pragma unroll
    for (int j = 0; j < 8; ++j) a[j] = 0.f;

    const size_t loff = (size_t)li * 8;
    uint4 kA0, vA0, kA1, vA1, kB0, vB0, kB1, vB1;
    int sN0, sN1, sN2, sN3;

    if (p0 < p1) {
        const int last = p1 - 1;
        // stage 0: indices + loads for edges p0..p0+3 (clamped)
        int i0 = p0, i1 = min(p0 + 1, last), i2 = min(p0 + 2, last), i3 = min(p0 + 3, last);
        int s0 = esrc[i0], s1 = esrc[i1], s2 = esrc[i2], s3 = esrc[i3];
        kA0 = *(const uint4*)(kt + (size_t)s0 * 128 + loff);
        vA0 = *(const uint4*)(vt + (size_t)s0 * 128 + loff);
        kA1 = *(const uint4*)(kt + (size_t)s1 * 128 + loff);
        vA1 = *(const uint4*)(vt + (size_t)s1 * 128 + loff);
        kB0 = *(const uint4*)(kt + (size_t)s2 * 128 + loff);
        vB0 = *(const uint4*)(vt + (size_t)s2 * 128 + loff);
        kB1 = *(const uint4*)(kt + (size_t)s3 * 128 + loff);
        vB1 = *(const uint4*)(vt + (size_t)s3 * 128 + loff);
        // stage 1: indices for edges p0+4..p0+7 (clamped) — in flight over compute
        sN0 = esrc[min(p0 + 4, last)];
        sN1 = esrc[min(p0 + 5, last)];
        sN2 = esrc[min(p0 + 6, last)];
        sN3 = esrc[min(p0 + 7, last)];

        for (int p = p0; p < p1; p += 4) {
            const int lastc = last;
            // ---- pair A: compute edges p, p+1; refill A with p+4, p+5
            EDGE_STEP(kA0, vA0, p);
            EDGE_STEP(kA1, vA1, p + 1);
            kA0 = *(const uint4*)(kt + (size_t)sN0 * 128 + loff);
            vA0 = *(const uint4*)(vt + (size_t)sN0 * 128 + loff);
            kA1 = *(const uint4*)(kt + (size_t)sN1 * 128 + loff);
            vA1 = *(const uint4*)(vt + (size_t)sN1 * 128 + loff);
            // indices for p+8, p+9 (next iteration's A refill)
            sN0 = esrc[min(p + 8, lastc)];
            sN1 = esrc[min(p + 9, lastc)];
            // ---- pair B: compute edges p+2, p+3; refill B with p+6, p+7
            EDGE_STEP(kB0, vB0, p + 2);
            EDGE_STEP(kB1, vB1, p + 3);
            kB0 = *(const uint4*)(kt + (size_t)sN2 * 128 + loff);
            vB0 = *(const uint4*)(vt + (size_t)sN2 * 128 + loff);
            kB1 = *(const uint4*)(kt + (size_t)sN3 * 128 + loff);
            vB1 = *(const uint4*)(vt + (size_t)sN3 * 128 + loff);
            sN2 = esrc[min(p + 10, lastc)];
            sN3 = esrc[min(p + 11, lastc)];
        }
    }

    float r = 1.0f / (s + 1e-16f);
    unsigned o[4];
    #pragma unroll
    for (int j = 0; j < 4; ++j) {
        us lo = f2bf(gelu_f(a[2 * j] * r));
        us hi = f2bf(gelu_f(a[2 * j + 1] * r));
        o[j] = (unsigned)lo | ((unsigned)hi << 16);
    }
    *(uint4*)(agg + (size_t)dst * 128 + li * 8) = make_uint4(o[0], o[1], o[2], o[3]);
}

// ---------------------------------------------------------------------------
// CSR build over the COMBINED dst space (feature dsts [0,NF), device [NF,NT)).
// ---------------------------------------------------------------------------
__global__ void k_count2(const int* __restrict__ dA, const int* __restrict__ dB,
                         int* __restrict__ cnt) {
    int i = blockIdx.x * 256 + threadIdx.x;
    if (i < NE) atomicAdd(&cnt[dA[i]], 1);
    else if (i < 2 * NE) atomicAdd(&cnt[NF + dB[i - NE]], 1);
}

__global__ void k_scan_partial(const int* __restrict__ cnt, int* __restrict__ part, int n) {
    __shared__ int sd[256];
    int t = threadIdx.x;
    int base = blockIdx.x * 1024 + t * 4;
    int s = 0;
    #pragma unroll
    for (int j = 0; j < 4; ++j) { int i = base + j; if (i < n) s += cnt[i]; }
    sd[t] = s; __syncthreads();
    for (int off = 128; off > 0; off >>= 1) {
        if (t < off) sd[t] += sd[t + off];
        __syncthreads();
    }
    if (t == 0) part[blockIdx.x] = sd[0];
}

__global__ void k_scan_small(int* part, int nb, int* row_start, int n) {
    if (threadIdx.x == 0 && blockIdx.x == 0) {
        int run = 0;
        for (int i = 0; i < nb; ++i) { int v = part[i]; part[i] = run; run += v; }
        row_start[n] = run;
    }
}

// writes row_start AND re-initializes cnt as the fill cursor (saves a copy pass)
__global__ void k_scan_final(int* __restrict__ cnt, const int* __restrict__ part,
                             int* __restrict__ row_start, int n) {
    __shared__ int sd[256];
    int t = threadIdx.x;
    int base = blockIdx.x * 1024 + t * 4;
    int v[4]; int s = 0;
    #pragma unroll
    for (int j = 0; j < 4; ++j) { int i = base + j; v[j] = (i < n) ? cnt[i] : 0; s += v[j]; }
    sd[t] = s; __syncthreads();
    for (int off = 1; off < 256; off <<= 1) {
        int add = (t >= off) ? sd[t - off] : 0;
        __syncthreads();
        sd[t] += add;
        __syncthreads();
    }
    int excl = part[blockIdx.x] + sd[t] - s;
    #pragma unroll
    for (int j = 0; j < 4; ++j) {
        int i = base + j;
        if (i < n) { row_start[i] = excl; cnt[i] = excl; }
        excl += v[j];
    }
}

__global__ void k_fill2(const int* __restrict__ sA, const int* __restrict__ dA,
                        const int* __restrict__ sB, const int* __restrict__ dB,
                        int* __restrict__ cursor, int* __restrict__ esrc) {
    int i = blockIdx.x * 256 + threadIdx.x;
    if (i < NE) {
        int p = atomicAdd(&cursor[dA[i]], 1);
        esrc[p] = sA[i];
    } else if (i < 2 * NE) {
        int j = i - NE;
        int p = atomicAdd(&cursor[NF + dB[j]], 1);
        esrc[p] = sB[j];
    }
}

// ---------------------------------------------------------------------------
extern "C" void kernel_launch(void* const* d_in, const int* in_sizes, int n_in,
                              void* d_out, int out_size, void* d_ws, size_t ws_size,
                              hipStream_t stream) {
    const float* x_device = (const float*)d_in[0];
    const float* x_feature = (const float*)d_in[1];
    const int* e_df_src = (const int*)d_in[2];
    const int* e_df_dst = (const int*)d_in[3];
    const int* e_fd_src = (const int*)d_in[4];
    const int* e_fd_dst = (const int*)d_in[5];
    const float* W_dev_in = (const float*)d_in[6];
    const float* b_dev_in = (const float*)d_in[7];
    const float* W_feat_in = (const float*)d_in[8];
    const float* b_feat_in = (const float*)d_in[9];
    const float* Wk = (const float*)d_in[10];
    const float* bk = (const float*)d_in[11];
    const float* Wq = (const float*)d_in[12];
    const float* bq = (const float*)d_in[13];
    const float* Wv = (const float*)d_in[14];
    const float* bv = (const float*)d_in[15];
    const float* a_rel = (const float*)d_in[16];
    const float* m_rel = (const float*)d_in[17];
    const float* p_rel = (const float*)d_in[18];
    const float* Wa = (const float*)d_in[19];
    const float* ba = (const float*)d_in[20];
    const float* skip = (const float*)d_in[21];
    const float* ln_g = (const float*)d_in[22];
    const float* ln_b = (const float*)d_in[23];
    const float* W_out = (const float*)d_in[24];
    const float* b_out = (const float*)d_in[25];

    char* ws = (char*)d_ws;
    size_t off = 0;
    auto alloc = [&](size_t bytes) -> void* {
        void* p = ws + off;
        off = (off + bytes + 255) & ~(size_t)255;
        return p;
    };
    us* xd     = (us*)alloc((size_t)ND * 128 * 2);
    us* xf     = (us*)alloc((size_t)NF * 128 * 2);
    us* qkv_d  = (us*)alloc((size_t)3 * ND * 128 * 2);
    us* qkv_f  = (us*)alloc((size_t)3 * NF * 128 * 2);
    us* agg_d  = (us*)alloc((size_t)ND * 128 * 2);
    us* agg_f  = (us*)alloc((size_t)NF * 128 * 2);
    us* WT     = (us*)alloc((size_t)18 * 16384 * 2);
    float* B_all = (float*)alloc(18 * 128 * 4);
    int* cnt    = (int*)alloc((size_t)NT * 4);
    int* rs     = (int*)alloc((size_t)(NT + 1) * 4);
    int* esrc   = (int*)alloc((size_t)(2 * NE + 8) * 4);   // +8 pad for clamped prefetch
    int* part   = (int*)alloc(128 * 4);

    // ---- combined CSR build (feature dsts 0..NF, device dsts NF..NT)
    hipMemsetAsync(cnt, 0, (size_t)NT * 4, stream);
    k_count2<<<(2 * NE + 255) / 256, 256, 0, stream>>>(e_df_dst, e_fd_dst, cnt);
    int nb = (NT + 1023) / 1024;
    k_scan_partial<<<nb, 256, 0, stream>>>(cnt, part, NT);
    k_scan_small<<<1, 64, 0, stream>>>(part, nb, rs, NT);
    k_scan_final<<<nb, 256, 0, stream>>>(cnt, part, rs, NT);
    k_fill2<<<(2 * NE + 255) / 256, 256, 0, stream>>>(e_df_src, e_df_dst,
                                                      e_fd_src, e_fd_dst, cnt, esrc);

    // ---- weight/bias prep
    prep_all<<<(18 * 16384 + 18 * 128 + 255) / 256, 256, 0, stream>>>(
        W_dev_in, W_feat_in, Wq, Wk, Wv, Wa,
        b_dev_in, b_feat_in, bq, bk, bv, ba,
        a_rel, m_rel, p_rel, WT, B_all);

    const int GBD = (ND + 127) / 128, GBF = (NF + 127) / 128;

    // ---- input projections + relu (fp32 in, bf16 out), both types fused
    mfma_gemm2<1, 1, 0><<<dim3(GBD + GBF, 1), 256, 0, stream>>>(
        x_device, x_feature, WT, B_all, xd, xf, ND, NF, GBD, 0,
        nullptr, nullptr, nullptr, nullptr, nullptr);

    for (int l = 0; l < 2; ++l) {
        // fused q/k/v for both types: ids q=2+lt, k=6+lt, v=10+lt
        mfma_gemm2<0, 0, 0><<<dim3(GBD + GBF, 3), 256, 0, stream>>>(
            xd, xf, WT, B_all, qkv_d, qkv_f, ND, NF, GBD, 2 + l * 2,
            nullptr, nullptr, nullptr, nullptr, nullptr);

        // both edge types in one dispatch
        edge_agg2<<<((NT * 16) + 255) / 256, 256, 0, stream>>>(
            qkv_f, qkv_d,
            qkv_f + (size_t)NF * 128, qkv_d + (size_t)ND * 128,
            qkv_f + (size_t)2 * NF * 128, qkv_d + (size_t)2 * ND * 128,
            rs, esrc, agg_f, agg_d);

        // o = gelu(agg) @ Wa + ba, fused skip+residual+LN, in place on x
        mfma_gemm2<0, 0, 1><<<dim3(GBD + GBF, 1), 256, 0, stream>>>(
            agg_d, agg_f, WT, B_all, nullptr, nullptr, ND, NF, GBD, 14 + l * 2,
            xd, xf, skip, ln_g, ln_b);
    }

    gemm_out_k<<<(ND + 7) / 8, 256, 0, stream>>>(xd, W_out, b_out, (float*)d_out, ND);
}

// Round 7
// 315.054 us; speedup vs baseline: 2.5517x; 1.2097x over previous
//
#include <hip/hip_runtime.h>
#include <math.h>

#define ND 20000
#define NF 50000
#define NE 400000
#define NT (NF + ND)     // combined dst nodes (feature first, then device)
// HID=128, H=8, D=16, L=2, IN=128, OUT=32

typedef __attribute__((ext_vector_type(8))) short short8;
typedef __attribute__((ext_vector_type(4))) float f32x4;
typedef unsigned short us;

static __device__ __forceinline__ us f2bf(float f) {
    unsigned u = __builtin_bit_cast(unsigned, f);
    u += 0x7FFF + ((u >> 16) & 1);          // round-to-nearest-even
    return (us)(u >> 16);
}
static __device__ __forceinline__ float bf2f(us h) {
    return __builtin_bit_cast(float, (unsigned)h << 16);
}
static __device__ __forceinline__ float bflo(unsigned u) {
    return __builtin_bit_cast(float, u << 16);
}
static __device__ __forceinline__ float bfhi(unsigned u) {
    return __builtin_bit_cast(float, u & 0xFFFF0000u);
}
static __device__ __forceinline__ float gelu_f(float x) {
    return 0.5f * x * (1.0f + erff(x * 0.70710678118654752f));
}

// ---------------------------------------------------------------------------
// Weight+bias prep. WT[id] stored XOR-SWIZZLED: element (c,k) at us-index
// (c*128 + k) ^ ((c&7)<<3)  (16B-granule swizzle, G4) so the GEMM can stage
// it to LDS with a LINEAR global_load_lds copy and read B-fragments as
// conflict-free ds_read_b128. B_all[id][128] fp32 biases (unswizzled).
// id 0: W_dev_in, 1: W_feat_in, 2+lt: Wq, 6+lt: WkF (a_rel & p_rel/4 folded),
// 10+lt: WvF (m_rel folded), 14+lt: Wa.   lt = l*2+t.
// ---------------------------------------------------------------------------
__global__ void prep_all(const float* __restrict__ W_dev_in, const float* __restrict__ W_feat_in,
                         const float* __restrict__ Wq, const float* __restrict__ Wk,
                         const float* __restrict__ Wv, const float* __restrict__ Wa,
                         const float* __restrict__ b_dev_in, const float* __restrict__ b_feat_in,
                         const float* __restrict__ bq, const float* __restrict__ bk,
                         const float* __restrict__ bv, const float* __restrict__ ba,
                         const float* __restrict__ a_rel, const float* __restrict__ m_rel,
                         const float* __restrict__ p_rel,
                         us* __restrict__ WT, float* __restrict__ B_all) {
    int idx = blockIdx.x * 256 + threadIdx.x;
    if (idx < 18 * 16384) {
        int k = idx & 127, c = (idx >> 7) & 127, id = idx >> 14;
        float val;
        if (id == 0) val = W_dev_in[k * 128 + c];
        else if (id == 1) val = W_feat_in[k * 128 + c];
        else if (id < 6) val = Wq[(id - 2) * 16384 + k * 128 + c];
        else if (id < 10) {
            int lt = id - 6, h = c >> 4, e = c & 15;
            const float* A = a_rel + (lt * 8 + h) * 256;
            const float* Ws = Wk + lt * 16384 + k * 128 + h * 16;
            float sm = 0.f;
            #pragma unroll
            for (int d = 0; d < 16; ++d) sm += Ws[d] * A[d * 16 + e];
            val = sm * p_rel[lt * 8 + h] * 0.25f;
        } else if (id < 14) {
            int lt = id - 10, h = c >> 4, e = c & 15;
            const float* A = m_rel + (lt * 8 + h) * 256;
            const float* Ws = Wv + lt * 16384 + k * 128 + h * 16;
            float sm = 0.f;
            #pragma unroll
            for (int d = 0; d < 16; ++d) sm += Ws[d] * A[d * 16 + e];
            val = sm;
        } else val = Wa[(id - 14) * 16384 + k * 128 + c];
        WT[(size_t)id * 16384 + (((c * 128 + k)) ^ ((c & 7) << 3))] = f2bf(val);
    } else {
        int j = idx - 18 * 16384;
        if (j >= 18 * 128) return;
        int c = j & 127, id = j >> 7;
        float v;
        if (id == 0) v = b_dev_in[c];
        else if (id == 1) v = b_feat_in[c];
        else if (id < 6) v = bq[(id - 2) * 128 + c];
        else if (id < 10) {
            int lt = id - 6, h = c >> 4, e = c & 15;
            const float* A = a_rel + (lt * 8 + h) * 256;
            const float* bs = bk + lt * 128 + h * 16;
            float sm = 0.f;
            #pragma unroll
            for (int d = 0; d < 16; ++d) sm += bs[d] * A[d * 16 + e];
            v = sm * p_rel[lt * 8 + h] * 0.25f;
        } else if (id < 14) {
            int lt = id - 10, h = c >> 4, e = c & 15;
            const float* A = m_rel + (lt * 8 + h) * 256;
            const float* bs = bv + lt * 128 + h * 16;
            float sm = 0.f;
            #pragma unroll
            for (int d = 0; d < 16; ++d) sm += bs[d] * A[d * 16 + e];
            v = sm;
        } else v = ba[(id - 14) * 128 + c];
        B_all[j] = v;
    }
}

// ---------------------------------------------------------------------------
// MFMA GEMM over BOTH node types in one dispatch. blockIdx.x < GB0 -> type 0
// (device), else type 1 (feature). blockIdx.y = output plane (q/k/v).
// Weight id = widbase + type + 4*blockIdx.y.
// W (32KB, pre-swizzled) is staged to LDS via global_load_lds width-16
// (linear copy), then B-fragments are conflict-free ds_read_b128.
// LNF=1: skip Y store; instead t = x + sk*o + (1-sk)*x, x = LN(t)*g + b
// written in place to the x buffer (row lives in one 16-lane shfl group).
// ---------------------------------------------------------------------------
template<int AF32, int RELU, int LNF>
__global__ __launch_bounds__(256) void mfma_gemm2(
    const void* __restrict__ X0, const void* __restrict__ X1,
    const us* __restrict__ WT0, const float* __restrict__ Ball,
    us* __restrict__ Y0, us* __restrict__ Y1,
    int N0, int N1, int GB0, int widbase,
    us* __restrict__ X0w, us* __restrict__ X1w,
    const float* __restrict__ skipv, const float* __restrict__ lng,
    const float* __restrict__ lnb) {
    __shared__ us Wlds[16384];                  // 32 KB, swizzled layout
    const int type = (blockIdx.x >= (unsigned)GB0) ? 1 : 0;
    const int bx = blockIdx.x - (type ? GB0 : 0);
    const int N = type ? N1 : N0;
    const void* Xv = type ? X1 : X0;
    const int wid = widbase + type + 4 * blockIdx.y;
    const us* WT = WT0 + (size_t)wid * 16384;
    const float* bias = Ball + wid * 128;

    const int lane = threadIdx.x & 63;
    const int wave = threadIdx.x >> 6;
    const int row_base = bx * 128 + wave * 32;
    const int l15 = lane & 15, lg = lane >> 4;
    const int kbase = lg * 8;

    // ---- stage W -> LDS: linear copy, each wave moves 8 KB (8 x 1KB calls)
    {
        const char* gsrc = (const char*)WT + wave * 8192 + lane * 16;
        char* ldst = (char*)Wlds + wave * 8192;
        #pragma unroll
        for (int i = 0; i < 8; ++i) {
            __builtin_amdgcn_global_load_lds(
                (const __attribute__((address_space(1))) void*)(gsrc + i * 1024),
                (__attribute__((address_space(3))) void*)(ldst + i * 1024),
                16, 0, 0);
        }
    }

    // ---- A fragments from global (overlaps the W staging)
    short8 a[2][4];
    #pragma unroll
    for (int mf = 0; mf < 2; ++mf) {
        int r = row_base + mf * 16 + l15;
        r = r < N ? r : N - 1;
        if (AF32) {
            const float* Xf = (const float*)Xv + (size_t)r * 128;
            #pragma unroll
            for (int kf = 0; kf < 4; ++kf) {
                float4 lo = *(const float4*)(Xf + kf * 32 + kbase);
                float4 hi = *(const float4*)(Xf + kf * 32 + kbase + 4);
                short8 t;
                t[0] = (short)f2bf(lo.x); t[1] = (short)f2bf(lo.y);
                t[2] = (short)f2bf(lo.z); t[3] = (short)f2bf(lo.w);
                t[4] = (short)f2bf(hi.x); t[5] = (short)f2bf(hi.y);
                t[6] = (short)f2bf(hi.z); t[7] = (short)f2bf(hi.w);
                a[mf][kf] = t;
            }
        } else {
            const us* Xb = (const us*)Xv + (size_t)r * 128;
            #pragma unroll
            for (int kf = 0; kf < 4; ++kf)
                a[mf][kf] = *(const short8*)(Xb + kf * 32 + kbase);
        }
    }

    __syncthreads();                            // drains global_load_lds too

    f32x4 acc[2][8];
    #pragma unroll
    for (int mf = 0; mf < 2; ++mf)
        #pragma unroll
        for (int cf = 0; cf < 8; ++cf) acc[mf][cf] = (f32x4){0.f, 0.f, 0.f, 0.f};

    const unsigned swz = (unsigned)((l15 & 7) << 4);   // byte-XOR for this lane's rows
    #pragma unroll
    for (int cf = 0; cf < 8; ++cf) {
        const unsigned rowbyte = (unsigned)((cf * 16 + l15) * 256 + kbase * 2);
        #pragma unroll
        for (int kf = 0; kf < 4; ++kf) {
            short8 b = *(const short8*)((const char*)Wlds + ((rowbyte + kf * 64) ^ swz));
            acc[0][cf] = __builtin_amdgcn_mfma_f32_16x16x32_bf16(a[0][kf], b, acc[0][cf], 0, 0, 0);
            acc[1][cf] = __builtin_amdgcn_mfma_f32_16x16x32_bf16(a[1][kf], b, acc[1][cf], 0, 0, 0);
        }
    }

    float bval[8];
    #pragma unroll
    for (int cf = 0; cf < 8; ++cf) bval[cf] = bias[cf * 16 + l15];

    if (LNF) {
        const int lt = widbase - 14 + type;     // = l*2 + type
        float sk = 1.f / (1.f + __expf(-skipv[lt]));
        float gv[8], bv2[8];
        #pragma unroll
        for (int cf = 0; cf < 8; ++cf) {
            gv[cf]  = lng[(size_t)lt * 128 + cf * 16 + l15];
            bv2[cf] = lnb[(size_t)lt * 128 + cf * 16 + l15];
        }
        us* xw = type ? X1w : X0w;
        #pragma unroll
        for (int mf = 0; mf < 2; ++mf)
            #pragma unroll
            for (int r = 0; r < 4; ++r) {
                int grow = row_base + mf * 16 + lg * 4 + r;   // uniform in shfl-16 group
                if (grow >= N) continue;
                float t[8];
                float sum = 0.f;
                #pragma unroll
                for (int cf = 0; cf < 8; ++cf) {
                    float o = acc[mf][cf][r] + bval[cf];
                    float x = bf2f(xw[(size_t)grow * 128 + cf * 16 + l15]);
                    t[cf] = (2.f - sk) * x + sk * o;
                    sum += t[cf];
                }
                sum += __shfl_xor(sum, 1); sum += __shfl_xor(sum, 2);
                sum += __shfl_xor(sum, 4); sum += __shfl_xor(sum, 8);
                float mean = sum * (1.0f / 128.0f);
                float vs = 0.f;
                #pragma unroll
                for (int cf = 0; cf < 8; ++cf) { t[cf] -= mean; vs += t[cf] * t[cf]; }
                vs += __shfl_xor(vs, 1); vs += __shfl_xor(vs, 2);
                vs += __shfl_xor(vs, 4); vs += __shfl_xor(vs, 8);
                float inv = rsqrtf(vs * (1.0f / 128.0f) + 1e-5f);
                #pragma unroll
                for (int cf = 0; cf < 8; ++cf)
                    xw[(size_t)grow * 128 + cf * 16 + l15] = f2bf(t[cf] * inv * gv[cf] + bv2[cf]);
            }
        return;
    }

    us* Yp = (type ? Y1 : Y0) + (size_t)blockIdx.y * N * 128;
    #pragma unroll
    for (int mf = 0; mf < 2; ++mf)
        #pragma unroll
        for (int r = 0; r < 4; ++r) {
            int grow = row_base + mf * 16 + lg * 4 + r;
            if (grow >= N) continue;
            #pragma unroll
            for (int cf = 0; cf < 8; ++cf) {
                float v = acc[mf][cf][r] + bval[cf];
                if (RELU) v = fmaxf(v, 0.f);
                Yp[(size_t)grow * 128 + cf * 16 + l15] = f2bf(v);
            }
        }
}

// ---------------------------------------------------------------------------
// Final head: Y[N,32](f32) = X(bf16)[N,128] @ W[128,32] + b
// ---------------------------------------------------------------------------
__global__ __launch_bounds__(256) void gemm_out_k(
    const us* __restrict__ X, const float* __restrict__ W,
    const float* __restrict__ bias, float* __restrict__ Y, int N) {
    __shared__ float Ws[128 * 32];
    __shared__ float Xs[8][128];
    const int tid = threadIdx.x;
    const int row0 = blockIdx.x * 8;
    #pragma unroll
    for (int it = 0; it < 16; ++it) Ws[it * 256 + tid] = W[it * 256 + tid];
    #pragma unroll
    for (int it = 0; it < 2; ++it) {
        int idx = it * 256 + tid;
        int rr = idx >> 6, kp = idx & 63;
        int gr = row0 + rr;
        unsigned u = (gr < N) ? *(const unsigned*)(X + (size_t)gr * 128 + kp * 2) : 0u;
        Xs[rr][kp * 2]     = bflo(u);
        Xs[rr][kp * 2 + 1] = bfhi(u);
    }
    __syncthreads();
    const int rr = tid >> 5, c = tid & 31;
    float acc = bias[c];
    #pragma unroll 8
    for (int k = 0; k < 128; ++k)
        acc = fmaf(Xs[rr][k], Ws[k * 32 + c], acc);
    int gr = row0 + rr;
    if (gr < N) Y[(size_t)gr * 32 + c] = acc;
}

// ---------------------------------------------------------------------------
// Edge aggregation, both edge types in one dispatch. 16 lanes per dst
// (4 dsts/wave); lane li owns dims [li*8, li*8+8). No-max softmax (logits
// LN-bounded). Depth-2x2 software pipeline, clamped loads, masked exp.
// ---------------------------------------------------------------------------
#define EDGE_STEP(kc, vc, pidx)                                        \
    {                                                                  \
        float part = qv[0] * bflo(kc.x);                               \
        part = fmaf(qv[1], bfhi(kc.x), part);                          \
        part = fmaf(qv[2], bflo(kc.y), part);                          \
        part = fmaf(qv[3], bfhi(kc.y), part);                          \
        part = fmaf(qv[4], bflo(kc.z), part);                          \
        part = fmaf(qv[5], bfhi(kc.z), part);                          \
        part = fmaf(qv[6], bflo(kc.w), part);                          \
        part = fmaf(qv[7], bfhi(kc.w), part);                          \
        part += __shfl_xor(part, 1);                                   \
        float w = ((pidx) < p1) ? __expf(part) : 0.f;                  \
        s += w;                                                        \
        a[0] = fmaf(w, bflo(vc.x), a[0]);                              \
        a[1] = fmaf(w, bfhi(vc.x), a[1]);                              \
        a[2] = fmaf(w, bflo(vc.y), a[2]);                              \
        a[3] = fmaf(w, bfhi(vc.y), a[3]);                              \
        a[4] = fmaf(w, bflo(vc.z), a[4]);                              \
        a[5] = fmaf(w, bfhi(vc.z), a[5]);                              \
        a[6] = fmaf(w, bflo(vc.w), a[6]);                              \
        a[7] = fmaf(w, bfhi(vc.w), a[7]);                              \
    }

__global__ __launch_bounds__(256) void edge_agg2(
    const us* __restrict__ qf, const us* __restrict__ qd,
    const us* __restrict__ ktf, const us* __restrict__ ktd,
    const us* __restrict__ vtf, const us* __restrict__ vtd,
    const int* __restrict__ rs, const int* __restrict__ esrc,
    us* __restrict__ aggf, us* __restrict__ aggd) {
    int g = (blockIdx.x * 256 + threadIdx.x) >> 4;
    int li = threadIdx.x & 15;
    if (g >= NT) return;
    const us *q, *kt, *vt; us* agg; int dst;
    if (g < NF) { dst = g;      q = qf; kt = ktd; vt = vtd; agg = aggf; }
    else        { dst = g - NF; q = qd; kt = ktf; vt = vtf; agg = aggd; }

    uint4 qb = *(const uint4*)(q + (size_t)dst * 128 + li * 8);
    float qv[8];
    qv[0] = bflo(qb.x); qv[1] = bfhi(qb.x);
    qv[2] = bflo(qb.y); qv[3] = bfhi(qb.y);
    qv[4] = bflo(qb.z); qv[5] = bfhi(qb.z);
    qv[6] = bflo(qb.w); qv[7] = bfhi(qb.w);

    const int p0 = rs[g], p1 = rs[g + 1];
    float s = 0.f;
    float a[8];
    #pragma unroll
    for (int j = 0; j < 8; ++j) a[j] = 0.f;

    const size_t loff = (size_t)li * 8;
    uint4 kA0, vA0, kA1, vA1, kB0, vB0, kB1, vB1;
    int sN0, sN1, sN2, sN3;

    if (p0 < p1) {
        const int last = p1 - 1;
        int i0 = p0, i1 = min(p0 + 1, last), i2 = min(p0 + 2, last), i3 = min(p0 + 3, last);
        int s0 = esrc[i0], s1 = esrc[i1], s2 = esrc[i2], s3 = esrc[i3];
        kA0 = *(const uint4*)(kt + (size_t)s0 * 128 + loff);
        vA0 = *(const uint4*)(vt + (size_t)s0 * 128 + loff);
        kA1 = *(const uint4*)(kt + (size_t)s1 * 128 + loff);
        vA1 = *(const uint4*)(vt + (size_t)s1 * 128 + loff);
        kB0 = *(const uint4*)(kt + (size_t)s2 * 128 + loff);
        vB0 = *(const uint4*)(vt + (size_t)s2 * 128 + loff);
        kB1 = *(const uint4*)(kt + (size_t)s3 * 128 + loff);
        vB1 = *(const uint4*)(vt + (size_t)s3 * 128 + loff);
        sN0 = esrc[min(p0 + 4, last)];
        sN1 = esrc[min(p0 + 5, last)];
        sN2 = esrc[min(p0 + 6, last)];
        sN3 = esrc[min(p0 + 7, last)];

        for (int p = p0; p < p1; p += 4) {
            const int lastc = last;
            EDGE_STEP(kA0, vA0, p);
            EDGE_STEP(kA1, vA1, p + 1);
            kA0 = *(const uint4*)(kt + (size_t)sN0 * 128 + loff);
            vA0 = *(const uint4*)(vt + (size_t)sN0 * 128 + loff);
            kA1 = *(const uint4*)(kt + (size_t)sN1 * 128 + loff);
            vA1 = *(const uint4*)(vt + (size_t)sN1 * 128 + loff);
            sN0 = esrc[min(p + 8, lastc)];
            sN1 = esrc[min(p + 9, lastc)];
            EDGE_STEP(kB0, vB0, p + 2);
            EDGE_STEP(kB1, vB1, p + 3);
            kB0 = *(const uint4*)(kt + (size_t)sN2 * 128 + loff);
            vB0 = *(const uint4*)(vt + (size_t)sN2 * 128 + loff);
            kB1 = *(const uint4*)(kt + (size_t)sN3 * 128 + loff);
            vB1 = *(const uint4*)(vt + (size_t)sN3 * 128 + loff);
            sN2 = esrc[min(p + 10, lastc)];
            sN3 = esrc[min(p + 11, lastc)];
        }
    }

    float r = 1.0f / (s + 1e-16f);
    unsigned o[4];
    #pragma unroll
    for (int j = 0; j < 4; ++j) {
        us lo = f2bf(gelu_f(a[2 * j] * r));
        us hi = f2bf(gelu_f(a[2 * j + 1] * r));
        o[j] = (unsigned)lo | ((unsigned)hi << 16);
    }
    *(uint4*)(agg + (size_t)dst * 128 + li * 8) = make_uint4(o[0], o[1], o[2], o[3]);
}

// ---------------------------------------------------------------------------
// CSR build over the COMBINED dst space (feature dsts [0,NF), device [NF,NT)).
// ---------------------------------------------------------------------------
__global__ void k_count2(const int* __restrict__ dA, const int* __restrict__ dB,
                         int* __restrict__ cnt) {
    int i = blockIdx.x * 256 + threadIdx.x;
    if (i < NE) atomicAdd(&cnt[dA[i]], 1);
    else if (i < 2 * NE) atomicAdd(&cnt[NF + dB[i - NE]], 1);
}

__global__ void k_scan_partial(const int* __restrict__ cnt, int* __restrict__ part, int n) {
    __shared__ int sd[256];
    int t = threadIdx.x;
    int base = blockIdx.x * 1024 + t * 4;
    int s = 0;
    #pragma unroll
    for (int j = 0; j < 4; ++j) { int i = base + j; if (i < n) s += cnt[i]; }
    sd[t] = s; __syncthreads();
    for (int off = 128; off > 0; off >>= 1) {
        if (t < off) sd[t] += sd[t + off];
        __syncthreads();
    }
    if (t == 0) part[blockIdx.x] = sd[0];
}

__global__ void k_scan_small(int* part, int nb, int* row_start, int n) {
    if (threadIdx.x == 0 && blockIdx.x == 0) {
        int run = 0;
        for (int i = 0; i < nb; ++i) { int v = part[i]; part[i] = run; run += v; }
        row_start[n] = run;
    }
}

// writes row_start AND re-initializes cnt as the fill cursor (saves a copy pass)
__global__ void k_scan_final(int* __restrict__ cnt, const int* __restrict__ part,
                             int* __restrict__ row_start, int n) {
    __shared__ int sd[256];
    int t = threadIdx.x;
    int base = blockIdx.x * 1024 + t * 4;
    int v[4]; int s = 0;
    #pragma unroll
    for (int j = 0; j < 4; ++j) { int i = base + j; v[j] = (i < n) ? cnt[i] : 0; s += v[j]; }
    sd[t] = s; __syncthreads();
    for (int off = 1; off < 256; off <<= 1) {
        int add = (t >= off) ? sd[t - off] : 0;
        __syncthreads();
        sd[t] += add;
        __syncthreads();
    }
    int excl = part[blockIdx.x] + sd[t] - s;
    #pragma unroll
    for (int j = 0; j < 4; ++j) {
        int i = base + j;
        if (i < n) { row_start[i] = excl; cnt[i] = excl; }
        excl += v[j];
    }
}

__global__ void k_fill2(const int* __restrict__ sA, const int* __restrict__ dA,
                        const int* __restrict__ sB, const int* __restrict__ dB,
                        int* __restrict__ cursor, int* __restrict__ esrc) {
    int i = blockIdx.x * 256 + threadIdx.x;
    if (i < NE) {
        int p = atomicAdd(&cursor[dA[i]], 1);
        esrc[p] = sA[i];
    } else if (i < 2 * NE) {
        int j = i - NE;
        int p = atomicAdd(&cursor[NF + dB[j]], 1);
        esrc[p] = sB[j];
    }
}

// ---------------------------------------------------------------------------
extern "C" void kernel_launch(void* const* d_in, const int* in_sizes, int n_in,
                              void* d_out, int out_size, void* d_ws, size_t ws_size,
                              hipStream_t stream) {
    const float* x_device = (const float*)d_in[0];
    const float* x_feature = (const float*)d_in[1];
    const int* e_df_src = (const int*)d_in[2];
    const int* e_df_dst = (const int*)d_in[3];
    const int* e_fd_src = (const int*)d_in[4];
    const int* e_fd_dst = (const int*)d_in[5];
    const float* W_dev_in = (const float*)d_in[6];
    const float* b_dev_in = (const float*)d_in[7];
    const float* W_feat_in = (const float*)d_in[8];
    const float* b_feat_in = (const float*)d_in[9];
    const float* Wk = (const float*)d_in[10];
    const float* bk = (const float*)d_in[11];
    const float* Wq = (const float*)d_in[12];
    const float* bq = (const float*)d_in[13];
    const float* Wv = (const float*)d_in[14];
    const float* bv = (const float*)d_in[15];
    const float* a_rel = (const float*)d_in[16];
    const float* m_rel = (const float*)d_in[17];
    const float* p_rel = (const float*)d_in[18];
    const float* Wa = (const float*)d_in[19];
    const float* ba = (const float*)d_in[20];
    const float* skip = (const float*)d_in[21];
    const float* ln_g = (const float*)d_in[22];
    const float* ln_b = (const float*)d_in[23];
    const float* W_out = (const float*)d_in[24];
    const float* b_out = (const float*)d_in[25];

    char* ws = (char*)d_ws;
    size_t off = 0;
    auto alloc = [&](size_t bytes) -> void* {
        void* p = ws + off;
        off = (off + bytes + 255) & ~(size_t)255;
        return p;
    };
    us* xd     = (us*)alloc((size_t)ND * 128 * 2);
    us* xf     = (us*)alloc((size_t)NF * 128 * 2);
    us* qkv_d  = (us*)alloc((size_t)3 * ND * 128 * 2);
    us* qkv_f  = (us*)alloc((size_t)3 * NF * 128 * 2);
    us* agg_d  = (us*)alloc((size_t)ND * 128 * 2);
    us* agg_f  = (us*)alloc((size_t)NF * 128 * 2);
    us* WT     = (us*)alloc((size_t)18 * 16384 * 2);
    float* B_all = (float*)alloc(18 * 128 * 4);
    int* cnt    = (int*)alloc((size_t)NT * 4);
    int* rs     = (int*)alloc((size_t)(NT + 1) * 4);
    int* esrc   = (int*)alloc((size_t)(2 * NE + 8) * 4);   // +8 pad for clamped prefetch
    int* part   = (int*)alloc(128 * 4);

    // ---- combined CSR build (feature dsts 0..NF, device dsts NF..NT)
    hipMemsetAsync(cnt, 0, (size_t)NT * 4, stream);
    k_count2<<<(2 * NE + 255) / 256, 256, 0, stream>>>(e_df_dst, e_fd_dst, cnt);
    int nb = (NT + 1023) / 1024;
    k_scan_partial<<<nb, 256, 0, stream>>>(cnt, part, NT);
    k_scan_small<<<1, 64, 0, stream>>>(part, nb, rs, NT);
    k_scan_final<<<nb, 256, 0, stream>>>(cnt, part, rs, NT);
    k_fill2<<<(2 * NE + 255) / 256, 256, 0, stream>>>(e_df_src, e_df_dst,
                                                      e_fd_src, e_fd_dst, cnt, esrc);

    // ---- weight/bias prep (swizzled WT)
    prep_all<<<(18 * 16384 + 18 * 128 + 255) / 256, 256, 0, stream>>>(
        W_dev_in, W_feat_in, Wq, Wk, Wv, Wa,
        b_dev_in, b_feat_in, bq, bk, bv, ba,
        a_rel, m_rel, p_rel, WT, B_all);

    const int GBD = (ND + 127) / 128, GBF = (NF + 127) / 128;

    // ---- input projections + relu (fp32 in, bf16 out), both types fused
    mfma_gemm2<1, 1, 0><<<dim3(GBD + GBF, 1), 256, 0, stream>>>(
        x_device, x_feature, WT, B_all, xd, xf, ND, NF, GBD, 0,
        nullptr, nullptr, nullptr, nullptr, nullptr);

    for (int l = 0; l < 2; ++l) {
        // fused q/k/v for both types: ids q=2+lt, k=6+lt, v=10+lt
        mfma_gemm2<0, 0, 0><<<dim3(GBD + GBF, 3), 256, 0, stream>>>(
            xd, xf, WT, B_all, qkv_d, qkv_f, ND, NF, GBD, 2 + l * 2,
            nullptr, nullptr, nullptr, nullptr, nullptr);

        // both edge types in one dispatch
        edge_agg2<<<((NT * 16) + 255) / 256, 256, 0, stream>>>(
            qkv_f, qkv_d,
            qkv_f + (size_t)NF * 128, qkv_d + (size_t)ND * 128,
            qkv_f + (size_t)2 * NF * 128, qkv_d + (size_t)2 * ND * 128,
            rs, esrc, agg_f, agg_d);

        // o = gelu(agg) @ Wa + ba, fused skip+residual+LN, in place on x
        mfma_gemm2<0, 0, 1><<<dim3(GBD + GBF, 1), 256, 0, stream>>>(
            agg_d, agg_f, WT, B_all, nullptr, nullptr, ND, NF, GBD, 14 + l * 2,
            xd, xf, skip, ln_g, ln_b);
    }

    gemm_out_k<<<(ND + 7) / 8, 256, 0, stream>>>(xd, W_out, b_out, (float*)d_out, ND);
}